// Round 20
// baseline (489.583 us; speedup 1.0000x reference)
//
#include <hip/hip_runtime.h>
#include <hip/hip_bf16.h>

typedef __hip_bfloat16 bf16;
typedef __attribute__((ext_vector_type(8))) short short8;
typedef __attribute__((ext_vector_type(4))) float f32x4;

__device__ __forceinline__ float b2f(bf16 v) { return __bfloat162float(v); }
__device__ __forceinline__ bf16 f2b(float v) { return __float2bfloat16(v); }
__device__ __forceinline__ short fbits(float v) {
  bf16 h = f2b(v); return *reinterpret_cast<short*>(&h);
}
__device__ __forceinline__ float sb2f(short s) {
  return b2f(*reinterpret_cast<bf16*>(&s));
}
// bijective XCD swizzle (m204): contiguous grid chunk per XCD
__device__ __forceinline__ int xcd_swz(int bid, int nwg) {
  int q = nwg >> 3, r = nwg & 7;
  int xcd = bid & 7, idx = bid >> 3;
  return (xcd < r ? xcd * (q + 1) : r * (q + 1) + (xcd - r) * q) + idx;
}

// ---------------------------------------------------------------------------
// Weight repack: w[co][ci][ky][kx] f32  ->  B-fragment order, hi/lo bf16 split.
// ---------------------------------------------------------------------------
__global__ __launch_bounds__(256) void repack_k(
    const float* __restrict__ w, short* __restrict__ Wr, int Cin, int Cout)
{
  const int nkc = Cin >> 5, ncof = Cout >> 4;
  const size_t gid = (size_t)blockIdx.x * 256 + threadIdx.x;
  const int lane = gid & 63;
  size_t r = gid >> 6;
  const int tap = r % 9; r /= 9;
  const int kcc = r % nkc; r /= nkc;
  const int cof = r % ncof;
  const int hl = r / ncof;
  const int co = cof * 16 + (lane & 15);
  short8 v;
#pragma unroll
  for (int j = 0; j < 8; ++j) {
    int ci = kcc * 32 + ((lane >> 4) * 8 + j);
    float wv = w[((size_t)co * Cin + ci) * 9 + tap];
    bf16 hi = f2b(wv);
    v[j] = hl ? fbits(wv - b2f(hi)) : *reinterpret_cast<short*>(&hi);
  }
  *reinterpret_cast<short8*>(Wr + gid * 8) = v;
}

// ---------------------------------------------------------------------------
// MFMA implicit-GEMM 3x3 conv, per-layer tile FM = R*CX/32, cog-major 1D
// grid + XCD swizzle. NEW: split-K (KS blocks share one output tile, each
// covering nkc/KS input-channel chunks; partial f32 accum -> combine pass).
// Raises TLP on small layers whose grid is otherwise occupancy-capped.
// Optional `stats` fused during staging (bit-exact inorm apply).
// S=1: conv on the SUBSAMPLED image (subsample-then-pad-conv).
// ---------------------------------------------------------------------------
template<int R, int CX, int S>
__global__ __launch_bounds__(256) void conv_mfma_k(
    const bf16* __restrict__ src, bf16* __restrict__ dst,
    const short8* __restrict__ Wr, const float* __restrict__ bias,
    const float2* __restrict__ stats, float* __restrict__ pout,
    int Win, int Hout, int Wout, int Cin, int Cout, int XT, int KS)
{
  constexpr int ROWS = R + 2;
  constexpr int COLS = CX + 2;
  constexpr int NGR = ROWS * 4 * COLS;
  constexpr int FM = (R * CX) / 32;
  __shared__ short8 a_s[NGR];

  // flat decomposition: ks (outer), cog, b, px-block (inner)
  const int ytn = Hout / R;
  const int nxy = XT * ytn;
  const int ncog = Cout >> 6;
  const int wg = xcd_swz(blockIdx.x, gridDim.x);
  const int ks = wg / (ncog * 4 * nxy);
  const int rem2 = wg - ks * (ncog * 4 * nxy);
  const int cog = rem2 / (4 * nxy);
  const int rem = rem2 - cog * (4 * nxy);
  const int b = rem / nxy;
  const int pxb = rem - b * nxy;
  const int xt = pxb % XT, yt = pxb / XT;
  const int x0 = xt * CX, y0 = yt * R;

  const int tid = threadIdx.x, lane = tid & 63, wid = tid >> 6;
  const int wm = wid & 1, wn = wid >> 1;
  const int nkc = Cin >> 5;
  const int nkcs = nkc / KS;                 // chunks for this block
  const int kc0 = ks * nkcs;
  const int ncof = Cout >> 4;
  const int l15 = lane & 15, lg = lane >> 4;

  f32x4 acc[FM][2] = {};

  int arow[FM], acolb[FM];
#pragma unroll
  for (int fm = 0; fm < FM; ++fm) {
    int p = wm * (R * CX / 2) + fm * 16 + l15;
    arow[fm] = p / CX;
    acolb[fm] = p % CX;
  }

  auto bload = [&](int hl, int fn, int kcc, int tap) -> short8 {
    int cof = cog * 4 + wn * 2 + fn;
    return Wr[((((size_t)hl * ncof + cof) * nkc + kcc) * 9 + tap) * 64 + lane];
  };

  short8 bc[2][2], bn_[2][2];
  bc[0][0] = bload(0, 0, kc0, 0); bc[0][1] = bload(0, 1, kc0, 0);
  bc[1][0] = bload(1, 0, kc0, 0); bc[1][1] = bload(1, 1, kc0, 0);

  for (int kc = kc0; kc < kc0 + nkcs; ++kc) {
    __syncthreads();
    for (int idx = tid; idx < NGR; idx += 256) {
      int g = idx & 3, cix = idx >> 2;
      int col = cix % COLS, row = cix / COLS;
      int sy = y0 + row - 1;
      int sx = x0 + col - 1;
      short8 v = {};
      if (sy >= 0 && sy < Hout && sx >= 0 && sx < Wout) {
        int ry = S ? 2 * sy : sy, rx = S ? 2 * sx : sx;
        v = *reinterpret_cast<const short8*>(
            reinterpret_cast<const short*>(src) +
            (((size_t)b * (S ? 2 * Hout : Hout) + ry) * Win + rx) * Cin +
            kc * 32 + g * 8);
        if (stats) {                     // fused inorm apply (bit-exact)
          const float2* st = stats + (size_t)b * Cin + kc * 32 + g * 8;
#pragma unroll
          for (int j = 0; j < 8; ++j)
            v[j] = fbits((sb2f(v[j]) - st[j].x) * st[j].y);
        }
      }
      a_s[(row * 4 + g) * COLS + col] = v;
    }
    __syncthreads();

#pragma unroll
    for (int tap = 0; tap < 9; ++tap) {
      const int dy = tap / 3, dx = tap % 3;
      int nt = tap + 1, nk = kc;
      if (nt == 9) { nt = 0; nk = (kc + 1 < kc0 + nkcs) ? kc + 1 : kc0; }
      bn_[0][0] = bload(0, 0, nk, nt); bn_[0][1] = bload(0, 1, nk, nt);
      bn_[1][0] = bload(1, 0, nk, nt); bn_[1][1] = bload(1, 1, nk, nt);
#pragma unroll
      for (int fm = 0; fm < FM; ++fm) {
        short8 a = a_s[((arow[fm] + dy) * 4 + lg) * COLS + acolb[fm] + dx];
        acc[fm][0] = __builtin_amdgcn_mfma_f32_16x16x32_bf16(a, bc[0][0], acc[fm][0], 0, 0, 0);
        acc[fm][0] = __builtin_amdgcn_mfma_f32_16x16x32_bf16(a, bc[1][0], acc[fm][0], 0, 0, 0);
        acc[fm][1] = __builtin_amdgcn_mfma_f32_16x16x32_bf16(a, bc[0][1], acc[fm][1], 0, 0, 0);
        acc[fm][1] = __builtin_amdgcn_mfma_f32_16x16x32_bf16(a, bc[1][1], acc[fm][1], 0, 0, 0);
      }
      bc[0][0] = bn_[0][0]; bc[0][1] = bn_[0][1];
      bc[1][0] = bn_[1][0]; bc[1][1] = bn_[1][1];
    }
  }

#pragma unroll
  for (int fn = 0; fn < 2; ++fn) {
    int co = cog * 64 + wn * 32 + fn * 16 + l15;
    float bs = bias[co];
#pragma unroll
    for (int fm = 0; fm < FM; ++fm) {
#pragma unroll
      for (int j = 0; j < 4; ++j) {
        int p = wm * (R * CX / 2) + fm * 16 + lg * 4 + j;
        int r = p / CX, x = p % CX;
        size_t oi = ((size_t)(b * Hout + y0 + r) * Wout + x0 + x) * Cout + co;
        if (pout) {                      // split-K: raw f32 partial
          pout[(size_t)ks * ((size_t)4 * Hout * Wout * Cout) + oi] = acc[fm][fn][j];
        } else {
          dst[oi] = f2b(fmaxf(acc[fm][fn][j] + bs, 0.f));
        }
      }
    }
  }
}

// combine 2 split-K partials: dst = bf16(relu(p0 + p1 + bias)), NHWC.
__global__ __launch_bounds__(256) void combine2_k(
    const float* __restrict__ p, const float* __restrict__ bias,
    bf16* __restrict__ dst, int n4, int Cout)
{
  int i = blockIdx.x * 256 + threadIdx.x;
  if (i >= n4) return;
  float4 a = reinterpret_cast<const float4*>(p)[i];
  float4 c = reinterpret_cast<const float4*>(p + (size_t)n4 * 4)[i];
  int co = (i * 4) & (Cout - 1);
  float4 bs = *reinterpret_cast<const float4*>(bias + co);
  short v0 = fbits(fmaxf(a.x + c.x + bs.x, 0.f));
  short v1 = fbits(fmaxf(a.y + c.y + bs.y, 0.f));
  short v2 = fbits(fmaxf(a.z + c.z + bs.z, 0.f));
  short v3 = fbits(fmaxf(a.w + c.w + bs.w, 0.f));
  short4 pk = make_short4(v0, v1, v2, v3);
  *reinterpret_cast<short4*>(reinterpret_cast<short*>(dst) + (size_t)i * 4) = pk;
}

// ---------------------------------------------------------------------------
// conv1a: Cin=2 VALU direct conv. NCHW f32 color (subsample-then-conv),
// NHWC bf16 out, bias+ReLU.
// ---------------------------------------------------------------------------
__global__ __launch_bounds__(256) void conv1a_k(
    const float* __restrict__ src, bf16* __restrict__ dst,
    const float* __restrict__ w, const float* __restrict__ bias)
{
  const int b = blockIdx.z, cog = blockIdx.y;
  const int ty0 = (blockIdx.x / 16) * 16, tx0 = (blockIdx.x % 16) * 16;
  const int tid = threadIdx.x, tx = tid & 15, ty = tid >> 4;

  __shared__ float in_s[2][18][18];
  __shared__ __align__(16) float w_s[2][3][3][16];

  for (int idx = tid; idx < 2 * 324; idx += 256) {
    int ci = idx / 324, r = idx - ci * 324;
    int iy = r / 18, ix = r - iy * 18;
    int gy = ty0 + iy - 1, gx = tx0 + ix - 1;
    float v = 0.f;
    if (gy >= 0 && gy < 256 && gx >= 0 && gx < 256)
      v = src[((size_t)(b * 2 + ci) * 512 + 2 * gy) * 512 + 2 * gx];
    in_s[ci][iy][ix] = v;
  }
  for (int idx = tid; idx < 2 * 144; idx += 256) {
    int co = idx & 15, r = idx >> 4;
    int ci = r / 9, k = r - ci * 9;
    w_s[ci][k / 3][k % 3][co] = w[(size_t)((cog * 16 + co) * 2 + ci) * 9 + k];
  }
  __syncthreads();

  float acc[16];
#pragma unroll
  for (int i = 0; i < 16; ++i) acc[i] = 0.f;
  for (int ci = 0; ci < 2; ++ci)
#pragma unroll
    for (int dy = 0; dy < 3; ++dy)
#pragma unroll
      for (int dx = 0; dx < 3; ++dx) {
        float v = in_s[ci][ty + dy][tx + dx];
        const float4* wv = (const float4*)(&w_s[ci][dy][dx][0]);
        float4 w0 = wv[0], w1 = wv[1], w2 = wv[2], w3 = wv[3];
        acc[0] = fmaf(v, w0.x, acc[0]);   acc[1] = fmaf(v, w0.y, acc[1]);
        acc[2] = fmaf(v, w0.z, acc[2]);   acc[3] = fmaf(v, w0.w, acc[3]);
        acc[4] = fmaf(v, w1.x, acc[4]);   acc[5] = fmaf(v, w1.y, acc[5]);
        acc[6] = fmaf(v, w1.z, acc[6]);   acc[7] = fmaf(v, w1.w, acc[7]);
        acc[8] = fmaf(v, w2.x, acc[8]);   acc[9] = fmaf(v, w2.y, acc[9]);
        acc[10] = fmaf(v, w2.z, acc[10]); acc[11] = fmaf(v, w2.w, acc[11]);
        acc[12] = fmaf(v, w3.x, acc[12]); acc[13] = fmaf(v, w3.y, acc[13]);
        acc[14] = fmaf(v, w3.z, acc[14]); acc[15] = fmaf(v, w3.w, acc[15]);
      }

  const int gy = ty0 + ty, gx = tx0 + tx;
  short8 s0, s1;
#pragma unroll
  for (int j = 0; j < 8; ++j) {
    s0[j] = fbits(fmaxf(acc[j] + bias[cog * 16 + j], 0.f));
    s1[j] = fbits(fmaxf(acc[8 + j] + bias[cog * 16 + 8 + j], 0.f));
  }
  short8* dp = reinterpret_cast<short8*>(
      reinterpret_cast<short*>(dst) + (((size_t)(b * 256 + gy) * 256 + gx) * 64 + cog * 16));
  dp[0] = s0; dp[1] = s1;
}

// ---------------------------------------------------------------------------
// InstanceNorm stats, 2-level (r17 vectorized stats1).
// ---------------------------------------------------------------------------
__global__ __launch_bounds__(256) void inorm_stats1_k(
    const bf16* __restrict__ x, float2* __restrict__ part,
    int HW, int C, int nb, int PC)
{
  const int b = blockIdx.y, pc = blockIdx.x;
  const int NC8 = C >> 3;
  const int pgc = 256 / NC8;
  const int c8 = (threadIdx.x % NC8) * 8;
  const int pg = threadIdx.x / NC8;
  const int chunk = HW / PC;
  const int p0 = pc * chunk;

  float s[8] = {}, ss[8] = {};
  for (int p = p0 + pg; p < p0 + chunk; p += pgc) {
    short8 v = *reinterpret_cast<const short8*>(
        reinterpret_cast<const short*>(x) + ((size_t)b * HW + p) * C + c8);
#pragma unroll
    for (int j = 0; j < 8; ++j) {
      float f = sb2f(v[j]);
      s[j] += f; ss[j] += f * f;
    }
  }
  __shared__ float sh[2][2048];
#pragma unroll
  for (int j = 0; j < 8; ++j) {
    sh[0][pg * C + c8 + j] = s[j];
    sh[1][pg * C + c8 + j] = ss[j];
  }
  __syncthreads();
  for (int c = threadIdx.x; c < C; c += 256) {
    float as = 0.f, aq = 0.f;
    for (int g = 0; g < pgc; ++g) { as += sh[0][g * C + c]; aq += sh[1][g * C + c]; }
    part[((size_t)pc * nb + b) * C + c] = make_float2(as, aq);
  }
}

__global__ __launch_bounds__(256) void inorm_stats2_k(
    const float2* __restrict__ part, float2* __restrict__ stats,
    int HW, int C, int PC, int nb)
{
  const int b = blockIdx.y, cg = blockIdx.x;
  const int c = threadIdx.x & 63, i = threadIdx.x >> 6;
  float s = 0.f, ss = 0.f;
  for (int pc = i; pc < PC; pc += 4) {
    float2 v = part[((size_t)pc * nb + b) * C + cg * 64 + c];
    s += v.x; ss += v.y;
  }
  __shared__ float sh[2][4][64];
  sh[0][i][c] = s; sh[1][i][c] = ss;
  __syncthreads();
  if (threadIdx.x < 64) {
    int cc = threadIdx.x;
    float s4 = sh[0][0][cc] + sh[0][1][cc] + sh[0][2][cc] + sh[0][3][cc];
    float q4 = sh[1][0][cc] + sh[1][1][cc] + sh[1][2][cc] + sh[1][3][cc];
    float m = s4 / (float)HW;
    float var = q4 / (float)HW - m * m;
    stats[(size_t)b * C + cg * 64 + cc] = make_float2(m, rsqrtf(var + 1e-5f));
  }
}

// generic apply: NHWC bf16 -> {NHWC bf16, NCHW f32} dests
__global__ __launch_bounds__(256) void inorm_apply_k(
    const bf16* __restrict__ x, const float2* __restrict__ stats, int HW, int C,
    bf16* __restrict__ dnhwc, float* __restrict__ fnchw)
{
  const int b = blockIdx.z, cg = blockIdx.y;
  const int c = cg * 64 + (threadIdx.x & 63);
  const int p = blockIdx.x * 4 + (threadIdx.x >> 6);
  const float2 st = stats[(size_t)b * C + c];
  const size_t ia = ((size_t)b * HW + p) * C + c;
  const float v = (b2f(x[ia]) - st.x) * st.y;
  if (dnhwc) dnhwc[ia] = f2b(v);
  if (fnchw) fnchw[((size_t)(b * C + c)) * HW + p] = v;
}

// ---------------------------------------------------------------------------
// Stage-2 apply: NHWC bf16 -> x-padded NCHW bf16 [b][c][128][144]
// ---------------------------------------------------------------------------
__global__ __launch_bounds__(256) void inorm_apply_pad_k(
    const bf16* __restrict__ x, const float2* __restrict__ stats,
    bf16* __restrict__ pad)
{
  const int b = blockIdx.z, cg = blockIdx.y, yy = blockIdx.x;
  const int tid = threadIdx.x;
  __shared__ bf16 t_s[64][130];
  __shared__ float2 st_s[64];
  if (tid < 64) st_s[tid] = stats[(size_t)b * 128 + cg * 64 + tid];
  __syncthreads();

  const int c8 = (tid & 7) * 8, px0 = tid >> 3;
#pragma unroll
  for (int pass = 0; pass < 4; ++pass) {
    int px = pass * 32 + px0;
    short8 v = *reinterpret_cast<const short8*>(
        reinterpret_cast<const short*>(x) +
        ((size_t)(b * 16384 + yy * 128 + px) * 128 + cg * 64 + c8));
#pragma unroll
    for (int j = 0; j < 8; ++j) {
      float2 st = st_s[c8 + j];
      t_s[c8 + j][px] = f2b((sb2f(v[j]) - st.x) * st.y);
    }
  }
  __syncthreads();

  for (int idx = tid; idx < 64 * 18; idx += 256) {
    int c = idx / 18, g = idx - (idx / 18) * 18;
    short8 v;
#pragma unroll
    for (int j = 0; j < 8; ++j) {
      int xx = g * 8 + j - 6;
      xx = xx < 0 ? 0 : (xx > 127 ? 127 : xx);
      v[j] = *reinterpret_cast<short*>(&t_s[c][xx]);
    }
    *reinterpret_cast<short8*>(
        reinterpret_cast<short*>(pad) +
        ((size_t)(b * 128 + cg * 64 + c) * 128 + yy) * 144 + g * 8) = v;
  }
}

// ---------------------------------------------------------------------------
// Correlation via MFMA banded GEMM (r11 structure, b0 batch-split).
// ---------------------------------------------------------------------------
__global__ __launch_bounds__(256) void corr_mfma_k(
    const float* __restrict__ corr, const bf16* __restrict__ pad,
    float* __restrict__ outc, bf16* __restrict__ outn, int b0)
{
  __shared__ __align__(16) char smem[26 * 64 * 16];
  short8* a_lds = reinterpret_cast<short8*>(smem);
  float* out_s = reinterpret_cast<float*>(smem);

  const int b = b0 + blockIdx.z;
  const int wg = xcd_swz(blockIdx.x, gridDim.x);
  const int y = wg >> 3, xt = wg & 7;
  const int x0 = xt * 16;
  const int tid = threadIdx.x, lane = tid & 63, wid = tid >> 6;
  const int l15 = lane & 15, lg = lane >> 4;

  for (int idx = tid; idx < 26 * 64; idx += 256) {
    short8 z = {};
    a_lds[idx] = z;
  }
  __syncthreads();

  unsigned short* ah = reinterpret_cast<unsigned short*>(a_lds);
  for (int idx = tid; idx < 169 * 16; idx += 256) {
    int t = idx >> 4, m = idx & 15;
    int dy = t / 13, dx = t - dy * 13;
    float f = corr[((size_t)b * 169 + t) * 16384 + y * 128 + x0 + m];
    bf16 hi = f2b(f);
    unsigned short hb = *reinterpret_cast<unsigned short*>(&hi);
    unsigned short lb = (unsigned short)fbits(f - b2f(hi));
    int k = m + dx;
    int ent = dy * 64 + (k >> 3) * 16 + m;
    ah[ent * 8 + (k & 7)] = hb;
    ah[(13 * 64 + ent) * 8 + (k & 7)] = lb;
  }
  __syncthreads();

  const int cg0 = wid * 2;
  f32x4 acc0 = {}, acc1 = {};
  const short* pb = reinterpret_cast<const short*>(pad);

  for (int dy = 0; dy < 13; ++dy) {
    int rowc = y + dy - 6; rowc = rowc < 0 ? 0 : (rowc > 127 ? 127 : rowc);
    short8 bhi = a_lds[dy * 64 + lane];
    short8 blo = a_lds[(13 + dy) * 64 + lane];
    size_t base0 = ((size_t)(b * 128 + cg0 * 16 + l15) * 128 + rowc) * 144
                   + x0 + lg * 8;
    short8 a0 = *reinterpret_cast<const short8*>(pb + base0);
    short8 a1 = *reinterpret_cast<const short8*>(pb + base0 + (size_t)16 * 128 * 144);
    acc0 = __builtin_amdgcn_mfma_f32_16x16x32_bf16(a0, bhi, acc0, 0, 0, 0);
    acc1 = __builtin_amdgcn_mfma_f32_16x16x32_bf16(a1, bhi, acc1, 0, 0, 0);
    acc0 = __builtin_amdgcn_mfma_f32_16x16x32_bf16(a0, blo, acc0, 0, 0, 0);
    acc1 = __builtin_amdgcn_mfma_f32_16x16x32_bf16(a1, blo, acc1, 0, 0, 0);
  }
  __syncthreads();

#pragma unroll
  for (int cgi = 0; cgi < 2; ++cgi) {
    f32x4 a = cgi ? acc1 : acc0;
    float* dst4 = out_s + l15 * 132 + (cg0 + cgi) * 16 + lg * 4;
    *reinterpret_cast<f32x4*>(dst4) = a;
  }
  __syncthreads();

  {
    int px_ = tid >> 4, c8 = (tid & 15) * 8;
    const float* row = out_s + px_ * 132 + c8;
    short8 v;
#pragma unroll
    for (int j = 0; j < 8; ++j) v[j] = fbits(row[j]);
    *reinterpret_cast<short8*>(
        reinterpret_cast<short*>(outn) +
        ((size_t)(b * 16384 + y * 128 + x0 + px_)) * 128 + c8) = v;
  }
  {
    int ch = tid >> 1, pg = tid & 1;
    float v0[4], v1[4];
#pragma unroll
    for (int i = 0; i < 4; ++i) v0[i] = out_s[(pg * 8 + i) * 132 + ch];
#pragma unroll
    for (int i = 0; i < 4; ++i) v1[i] = out_s[(pg * 8 + 4 + i) * 132 + ch];
    float* dst = outc + ((size_t)(b * 128 + ch)) * 16384 + y * 128 + x0 + pg * 8;
    *reinterpret_cast<float4*>(dst) = make_float4(v0[0], v0[1], v0[2], v0[3]);
    *reinterpret_cast<float4*>(dst + 4) = make_float4(v1[0], v1[1], v1[2], v1[3]);
  }
}

// ---------------------------------------------------------------------------
// Workspace plan — BYTES, liveness-proven. Peak 62.9 MB.
//   PK (split-K partials, 2 x 8.39 MB) lives in P0 [10,26.8) during stage 4
//   (P0's corr output is dead after conv3a reads it).
// ---------------------------------------------------------------------------
extern "C" void kernel_launch(void* const* d_in, const int* in_sizes, int n_in,
                              void* d_out, int out_size, void* d_ws, size_t ws_size,
                              hipStream_t stream) {
  const float* color = (const float*)d_in[0];
  const float* corr  = (const float*)d_in[1];
  const float* w1a = (const float*)d_in[2];  const float* b1a = (const float*)d_in[3];
  const float* w1b = (const float*)d_in[4];  const float* b1b = (const float*)d_in[5];
  const float* w2a = (const float*)d_in[6];  const float* b2a = (const float*)d_in[7];
  const float* w2b = (const float*)d_in[8];  const float* b2b = (const float*)d_in[9];
  const float* w3a = (const float*)d_in[10]; const float* b3a = (const float*)d_in[11];
  const float* w3b = (const float*)d_in[12]; const float* b3b = (const float*)d_in[13];
  const float* w4a = (const float*)d_in[14]; const float* b4a = (const float*)d_in[15];
  const float* w4b = (const float*)d_in[16]; const float* b4b = (const float*)d_in[17];

  float* out = (float*)d_out;
  char* ws = (char*)d_ws;
  const size_t MB = 1048576;
  float2* stats = (float2*)ws;
  float2* part  = (float2*)(ws + (64 << 10));
  short*  WrS   = (short*)(ws + (256 << 10));
  const short8* Wr = (const short8*)WrS;
  bf16* P0 = (bf16*)(ws + 10 * MB);
  bf16* P1 = (bf16*)(ws + 27 * MB);
  bf16* P2 = (bf16*)(ws + 44 * MB);
  float* PK = (float*)(ws + 10 * MB);        // split-K partials (stage 4)
  bf16* X1 = P0;
  bf16* X2 = (bf16*)d_out;
  const float2* nost = (const float2*)nullptr;
  float* nop = (float*)nullptr;

  // ---- stage 1: conv1a -> conv1b(FM8) -> stats (apply fused into conv2a) --
  conv1a_k<<<dim3(256, 4, 4), 256, 0, stream>>>(color, X1, w1a, b1a);
  repack_k<<<36, 256, 0, stream>>>(w1b, WrS, 64, 64);
  conv_mfma_k<16, 16, 0><<<1024, 256, 0, stream>>>(
      X1, X2, Wr, b1b, nost, nop, 256, 256, 256, 64, 64, 16, 1);
  inorm_stats1_k<<<dim3(64, 4), 256, 0, stream>>>(X2, part, 65536, 64, 4, 64);
  inorm_stats2_k<<<dim3(1, 4), 256, 0, stream>>>(part, stats, 65536, 64, 64, 4);

  // ---- stage 2: conv2a(FM8, raw X2+stats) -> conv2b(FM8) -> pad apply ----
  repack_k<<<72, 256, 0, stream>>>(w2a, WrS, 64, 128);
  conv_mfma_k<16, 16, 1><<<512, 256, 0, stream>>>(
      X2, P0, Wr, b2a, stats, nop, 256, 128, 128, 64, 128, 8, 1);
  repack_k<<<144, 256, 0, stream>>>(w2b, WrS, 128, 128);
  conv_mfma_k<16, 16, 0><<<512, 256, 0, stream>>>(
      P0, P1, Wr, b2b, nost, nop, 128, 128, 128, 128, 128, 8, 1);
  inorm_stats1_k<<<dim3(64, 4), 256, 0, stream>>>(P1, part, 16384, 128, 4, 64);
  inorm_stats2_k<<<dim3(2, 4), 256, 0, stream>>>(part, stats, 16384, 128, 64, 4);
  inorm_apply_pad_k<<<dim3(128, 2, 4), 256, 0, stream>>>(P1, stats, P2);

  // ---- correlation (MFMA), split into 2 half-batch dispatches ----
  corr_mfma_k<<<dim3(128 * 8, 1, 2), 256, 0, stream>>>(corr, P2, out, P0, 0);
  corr_mfma_k<<<dim3(128 * 8, 1, 2), 256, 0, stream>>>(corr, P2, out, P0, 2);

  // ---- stage 3: conv3a(FM4) -> conv3b(FM4) -> stats; apply f32 only ----
  repack_k<<<288, 256, 0, stream>>>(w3a, WrS, 128, 256);
  conv_mfma_k<8, 16, 1><<<512, 256, 0, stream>>>(
      P0, P1, Wr, b3a, nost, nop, 128, 64, 64, 128, 256, 4, 1);
  repack_k<<<576, 256, 0, stream>>>(w3b, WrS, 256, 256);
  conv_mfma_k<8, 16, 0><<<512, 256, 0, stream>>>(
      P1, P2, Wr, b3b, nost, nop, 64, 64, 64, 256, 256, 4, 1);
  inorm_stats1_k<<<dim3(32, 4), 256, 0, stream>>>(P2, part, 4096, 256, 4, 32);
  inorm_stats2_k<<<dim3(4, 4), 256, 0, stream>>>(part, stats, 4096, 256, 32, 4);
  inorm_apply_k<<<dim3(1024, 4, 4), 256, 0, stream>>>(
      P2, stats, 4096, 256, (bf16*)nullptr, out + 8388608);

  // ---- stage 4: conv4a/conv4b split-K=2 (partials in PK=P0, combine) ----
  repack_k<<<1152, 256, 0, stream>>>(w4a, WrS, 256, 512);
  conv_mfma_k<4, 16, 1><<<1024, 256, 0, stream>>>(
      P2, (bf16*)nullptr, Wr, b4a, stats, PK, 64, 32, 32, 256, 512, 2, 2);
  combine2_k<<<2048, 256, 0, stream>>>(PK, b4a, P1, 524288, 512);
  repack_k<<<2304, 256, 0, stream>>>(w4b, WrS, 512, 512);
  conv_mfma_k<4, 16, 0><<<1024, 256, 0, stream>>>(
      P1, (bf16*)nullptr, Wr, b4b, nost, PK, 32, 32, 32, 512, 512, 2, 2);
  combine2_k<<<2048, 256, 0, stream>>>(PK, b4b, P2, 524288, 512);
  inorm_stats1_k<<<dim3(32, 4), 256, 0, stream>>>(P2, part, 1024, 512, 4, 32);
  inorm_stats2_k<<<dim3(8, 4), 256, 0, stream>>>(part, stats, 1024, 512, 32, 4);
  inorm_apply_k<<<dim3(256, 8, 4), 256, 0, stream>>>(
      P2, stats, 1024, 512, (bf16*)nullptr, out + 12582912);
}

// Round 21
// 443.483 us; speedup vs baseline: 1.1039x; 1.1039x over previous
//
#include <hip/hip_runtime.h>
#include <hip/hip_bf16.h>

typedef __hip_bfloat16 bf16;
typedef __attribute__((ext_vector_type(8))) short short8;
typedef __attribute__((ext_vector_type(4))) float f32x4;

__device__ __forceinline__ float b2f(bf16 v) { return __bfloat162float(v); }
__device__ __forceinline__ bf16 f2b(float v) { return __float2bfloat16(v); }
__device__ __forceinline__ short fbits(float v) {
  bf16 h = f2b(v); return *reinterpret_cast<short*>(&h);
}
__device__ __forceinline__ float sb2f(short s) {
  return b2f(*reinterpret_cast<bf16*>(&s));
}
// bijective XCD swizzle (m204): contiguous grid chunk per XCD
__device__ __forceinline__ int xcd_swz(int bid, int nwg) {
  int q = nwg >> 3, r = nwg & 7;
  int xcd = bid & 7, idx = bid >> 3;
  return (xcd < r ? xcd * (q + 1) : r * (q + 1) + (xcd - r) * q) + idx;
}

// ---------------------------------------------------------------------------
// Weight repack: w[co][ci][ky][kx] f32 -> B-fragment order; nhl=2: hi+lo
// bf16 split (f32-precision weights); nhl=1: hi only (half MFMA/traffic).
// ---------------------------------------------------------------------------
__global__ __launch_bounds__(256) void repack_k(
    const float* __restrict__ w, short* __restrict__ Wr, int Cin, int Cout,
    int nhl)
{
  const int nkc = Cin >> 5, ncof = Cout >> 4;
  const size_t gid = (size_t)blockIdx.x * 256 + threadIdx.x;
  const int lane = gid & 63;
  size_t r = gid >> 6;
  const int tap = r % 9; r /= 9;
  const int kcc = r % nkc; r /= nkc;
  const int cof = r % ncof;
  const int hl = r / ncof;
  if (hl >= nhl) return;
  const int co = cof * 16 + (lane & 15);
  short8 v;
#pragma unroll
  for (int j = 0; j < 8; ++j) {
    int ci = kcc * 32 + ((lane >> 4) * 8 + j);
    float wv = w[((size_t)co * Cin + ci) * 9 + tap];
    bf16 hi = f2b(wv);
    v[j] = hl ? fbits(wv - b2f(hi)) : *reinterpret_cast<short*>(&hi);
  }
  *reinterpret_cast<short8*>(Wr + gid * 8) = v;
}

// ---------------------------------------------------------------------------
// MFMA implicit-GEMM 3x3 conv, per-layer tile FM = R*CX/32, cog-major 1D
// grid + XCD swizzle, optional split-K (KS), optional fused inorm (stats).
// LO=1: hi+lo weight pair (f32-precision); LO=0: hi only (half MFMA work).
// S=1: conv on the SUBSAMPLED image (subsample-then-pad-conv).
// ---------------------------------------------------------------------------
template<int R, int CX, int S, int LO>
__global__ __launch_bounds__(256) void conv_mfma_k(
    const bf16* __restrict__ src, bf16* __restrict__ dst,
    const short8* __restrict__ Wr, const float* __restrict__ bias,
    const float2* __restrict__ stats, float* __restrict__ pout,
    int Win, int Hout, int Wout, int Cin, int Cout, int XT, int KS)
{
  constexpr int ROWS = R + 2;
  constexpr int COLS = CX + 2;
  constexpr int NGR = ROWS * 4 * COLS;
  constexpr int FM = (R * CX) / 32;
  __shared__ short8 a_s[NGR];

  const int ytn = Hout / R;
  const int nxy = XT * ytn;
  const int ncog = Cout >> 6;
  const int wg = xcd_swz(blockIdx.x, gridDim.x);
  const int ks = wg / (ncog * 4 * nxy);
  const int rem2 = wg - ks * (ncog * 4 * nxy);
  const int cog = rem2 / (4 * nxy);
  const int rem = rem2 - cog * (4 * nxy);
  const int b = rem / nxy;
  const int pxb = rem - b * nxy;
  const int xt = pxb % XT, yt = pxb / XT;
  const int x0 = xt * CX, y0 = yt * R;

  const int tid = threadIdx.x, lane = tid & 63, wid = tid >> 6;
  const int wm = wid & 1, wn = wid >> 1;
  const int nkc = Cin >> 5;
  const int nkcs = nkc / KS;
  const int kc0 = ks * nkcs;
  const int ncof = Cout >> 4;
  const int l15 = lane & 15, lg = lane >> 4;

  f32x4 acc[FM][2] = {};

  int arow[FM], acolb[FM];
#pragma unroll
  for (int fm = 0; fm < FM; ++fm) {
    int p = wm * (R * CX / 2) + fm * 16 + l15;
    arow[fm] = p / CX;
    acolb[fm] = p % CX;
  }

  auto bload = [&](int hl, int fn, int kcc, int tap) -> short8 {
    int cof = cog * 4 + wn * 2 + fn;
    return Wr[((((size_t)hl * ncof + cof) * nkc + kcc) * 9 + tap) * 64 + lane];
  };

  short8 bc[2][2], bn_[2][2];
  bc[0][0] = bload(0, 0, kc0, 0); bc[0][1] = bload(0, 1, kc0, 0);
  if (LO) { bc[1][0] = bload(1, 0, kc0, 0); bc[1][1] = bload(1, 1, kc0, 0); }

  for (int kc = kc0; kc < kc0 + nkcs; ++kc) {
    __syncthreads();
    for (int idx = tid; idx < NGR; idx += 256) {
      int g = idx & 3, cix = idx >> 2;
      int col = cix % COLS, row = cix / COLS;
      int sy = y0 + row - 1;
      int sx = x0 + col - 1;
      short8 v = {};
      if (sy >= 0 && sy < Hout && sx >= 0 && sx < Wout) {
        int ry = S ? 2 * sy : sy, rx = S ? 2 * sx : sx;
        v = *reinterpret_cast<const short8*>(
            reinterpret_cast<const short*>(src) +
            (((size_t)b * (S ? 2 * Hout : Hout) + ry) * Win + rx) * Cin +
            kc * 32 + g * 8);
        if (stats) {                     // fused inorm apply (bit-exact)
          const float2* st = stats + (size_t)b * Cin + kc * 32 + g * 8;
#pragma unroll
          for (int j = 0; j < 8; ++j)
            v[j] = fbits((sb2f(v[j]) - st[j].x) * st[j].y);
        }
      }
      a_s[(row * 4 + g) * COLS + col] = v;
    }
    __syncthreads();

#pragma unroll
    for (int tap = 0; tap < 9; ++tap) {
      const int dy = tap / 3, dx = tap % 3;
      int nt = tap + 1, nk = kc;
      if (nt == 9) { nt = 0; nk = (kc + 1 < kc0 + nkcs) ? kc + 1 : kc0; }
      bn_[0][0] = bload(0, 0, nk, nt); bn_[0][1] = bload(0, 1, nk, nt);
      if (LO) { bn_[1][0] = bload(1, 0, nk, nt); bn_[1][1] = bload(1, 1, nk, nt); }
#pragma unroll
      for (int fm = 0; fm < FM; ++fm) {
        short8 a = a_s[((arow[fm] + dy) * 4 + lg) * COLS + acolb[fm] + dx];
        acc[fm][0] = __builtin_amdgcn_mfma_f32_16x16x32_bf16(a, bc[0][0], acc[fm][0], 0, 0, 0);
        if (LO)
          acc[fm][0] = __builtin_amdgcn_mfma_f32_16x16x32_bf16(a, bc[1][0], acc[fm][0], 0, 0, 0);
        acc[fm][1] = __builtin_amdgcn_mfma_f32_16x16x32_bf16(a, bc[0][1], acc[fm][1], 0, 0, 0);
        if (LO)
          acc[fm][1] = __builtin_amdgcn_mfma_f32_16x16x32_bf16(a, bc[1][1], acc[fm][1], 0, 0, 0);
      }
      bc[0][0] = bn_[0][0]; bc[0][1] = bn_[0][1];
      if (LO) { bc[1][0] = bn_[1][0]; bc[1][1] = bn_[1][1]; }
    }
  }

#pragma unroll
  for (int fn = 0; fn < 2; ++fn) {
    int co = cog * 64 + wn * 32 + fn * 16 + l15;
    float bs = bias[co];
#pragma unroll
    for (int fm = 0; fm < FM; ++fm) {
#pragma unroll
      for (int j = 0; j < 4; ++j) {
        int p = wm * (R * CX / 2) + fm * 16 + lg * 4 + j;
        int r = p / CX, x = p % CX;
        size_t oi = ((size_t)(b * Hout + y0 + r) * Wout + x0 + x) * Cout + co;
        if (pout) {
          pout[(size_t)ks * ((size_t)4 * Hout * Wout * Cout) + oi] = acc[fm][fn][j];
        } else {
          dst[oi] = f2b(fmaxf(acc[fm][fn][j] + bs, 0.f));
        }
      }
    }
  }
}

// combine 2 split-K partials: dst = bf16(relu(p0 + p1 + bias)), NHWC.
__global__ __launch_bounds__(256) void combine2_k(
    const float* __restrict__ p, const float* __restrict__ bias,
    bf16* __restrict__ dst, int n4, int Cout)
{
  int i = blockIdx.x * 256 + threadIdx.x;
  if (i >= n4) return;
  float4 a = reinterpret_cast<const float4*>(p)[i];
  float4 c = reinterpret_cast<const float4*>(p + (size_t)n4 * 4)[i];
  int co = (i * 4) & (Cout - 1);
  float4 bs = *reinterpret_cast<const float4*>(bias + co);
  short v0 = fbits(fmaxf(a.x + c.x + bs.x, 0.f));
  short v1 = fbits(fmaxf(a.y + c.y + bs.y, 0.f));
  short v2 = fbits(fmaxf(a.z + c.z + bs.z, 0.f));
  short v3 = fbits(fmaxf(a.w + c.w + bs.w, 0.f));
  short4 pk = make_short4(v0, v1, v2, v3);
  *reinterpret_cast<short4*>(reinterpret_cast<short*>(dst) + (size_t)i * 4) = pk;
}

// ---------------------------------------------------------------------------
// conv1a: Cin=2 VALU direct conv. NCHW f32 color (subsample-then-conv),
// NHWC bf16 out, bias+ReLU.
// ---------------------------------------------------------------------------
__global__ __launch_bounds__(256) void conv1a_k(
    const float* __restrict__ src, bf16* __restrict__ dst,
    const float* __restrict__ w, const float* __restrict__ bias)
{
  const int b = blockIdx.z, cog = blockIdx.y;
  const int ty0 = (blockIdx.x / 16) * 16, tx0 = (blockIdx.x % 16) * 16;
  const int tid = threadIdx.x, tx = tid & 15, ty = tid >> 4;

  __shared__ float in_s[2][18][18];
  __shared__ __align__(16) float w_s[2][3][3][16];

  for (int idx = tid; idx < 2 * 324; idx += 256) {
    int ci = idx / 324, r = idx - ci * 324;
    int iy = r / 18, ix = r - iy * 18;
    int gy = ty0 + iy - 1, gx = tx0 + ix - 1;
    float v = 0.f;
    if (gy >= 0 && gy < 256 && gx >= 0 && gx < 256)
      v = src[((size_t)(b * 2 + ci) * 512 + 2 * gy) * 512 + 2 * gx];
    in_s[ci][iy][ix] = v;
  }
  for (int idx = tid; idx < 2 * 144; idx += 256) {
    int co = idx & 15, r = idx >> 4;
    int ci = r / 9, k = r - ci * 9;
    w_s[ci][k / 3][k % 3][co] = w[(size_t)((cog * 16 + co) * 2 + ci) * 9 + k];
  }
  __syncthreads();

  float acc[16];
#pragma unroll
  for (int i = 0; i < 16; ++i) acc[i] = 0.f;
  for (int ci = 0; ci < 2; ++ci)
#pragma unroll
    for (int dy = 0; dy < 3; ++dy)
#pragma unroll
      for (int dx = 0; dx < 3; ++dx) {
        float v = in_s[ci][ty + dy][tx + dx];
        const float4* wv = (const float4*)(&w_s[ci][dy][dx][0]);
        float4 w0 = wv[0], w1 = wv[1], w2 = wv[2], w3 = wv[3];
        acc[0] = fmaf(v, w0.x, acc[0]);   acc[1] = fmaf(v, w0.y, acc[1]);
        acc[2] = fmaf(v, w0.z, acc[2]);   acc[3] = fmaf(v, w0.w, acc[3]);
        acc[4] = fmaf(v, w1.x, acc[4]);   acc[5] = fmaf(v, w1.y, acc[5]);
        acc[6] = fmaf(v, w1.z, acc[6]);   acc[7] = fmaf(v, w1.w, acc[7]);
        acc[8] = fmaf(v, w2.x, acc[8]);   acc[9] = fmaf(v, w2.y, acc[9]);
        acc[10] = fmaf(v, w2.z, acc[10]); acc[11] = fmaf(v, w2.w, acc[11]);
        acc[12] = fmaf(v, w3.x, acc[12]); acc[13] = fmaf(v, w3.y, acc[13]);
        acc[14] = fmaf(v, w3.z, acc[14]); acc[15] = fmaf(v, w3.w, acc[15]);
      }

  const int gy = ty0 + ty, gx = tx0 + tx;
  short8 s0, s1;
#pragma unroll
  for (int j = 0; j < 8; ++j) {
    s0[j] = fbits(fmaxf(acc[j] + bias[cog * 16 + j], 0.f));
    s1[j] = fbits(fmaxf(acc[8 + j] + bias[cog * 16 + 8 + j], 0.f));
  }
  short8* dp = reinterpret_cast<short8*>(
      reinterpret_cast<short*>(dst) + (((size_t)(b * 256 + gy) * 256 + gx) * 64 + cog * 16));
  dp[0] = s0; dp[1] = s1;
}

// ---------------------------------------------------------------------------
// InstanceNorm stats, 2-level (r17 vectorized stats1).
// ---------------------------------------------------------------------------
__global__ __launch_bounds__(256) void inorm_stats1_k(
    const bf16* __restrict__ x, float2* __restrict__ part,
    int HW, int C, int nb, int PC)
{
  const int b = blockIdx.y, pc = blockIdx.x;
  const int NC8 = C >> 3;
  const int pgc = 256 / NC8;
  const int c8 = (threadIdx.x % NC8) * 8;
  const int pg = threadIdx.x / NC8;
  const int chunk = HW / PC;
  const int p0 = pc * chunk;

  float s[8] = {}, ss[8] = {};
  for (int p = p0 + pg; p < p0 + chunk; p += pgc) {
    short8 v = *reinterpret_cast<const short8*>(
        reinterpret_cast<const short*>(x) + ((size_t)b * HW + p) * C + c8);
#pragma unroll
    for (int j = 0; j < 8; ++j) {
      float f = sb2f(v[j]);
      s[j] += f; ss[j] += f * f;
    }
  }
  __shared__ float sh[2][2048];
#pragma unroll
  for (int j = 0; j < 8; ++j) {
    sh[0][pg * C + c8 + j] = s[j];
    sh[1][pg * C + c8 + j] = ss[j];
  }
  __syncthreads();
  for (int c = threadIdx.x; c < C; c += 256) {
    float as = 0.f, aq = 0.f;
    for (int g = 0; g < pgc; ++g) { as += sh[0][g * C + c]; aq += sh[1][g * C + c]; }
    part[((size_t)pc * nb + b) * C + c] = make_float2(as, aq);
  }
}

__global__ __launch_bounds__(256) void inorm_stats2_k(
    const float2* __restrict__ part, float2* __restrict__ stats,
    int HW, int C, int PC, int nb)
{
  const int b = blockIdx.y, cg = blockIdx.x;
  const int c = threadIdx.x & 63, i = threadIdx.x >> 6;
  float s = 0.f, ss = 0.f;
  for (int pc = i; pc < PC; pc += 4) {
    float2 v = part[((size_t)pc * nb + b) * C + cg * 64 + c];
    s += v.x; ss += v.y;
  }
  __shared__ float sh[2][4][64];
  sh[0][i][c] = s; sh[1][i][c] = ss;
  __syncthreads();
  if (threadIdx.x < 64) {
    int cc = threadIdx.x;
    float s4 = sh[0][0][cc] + sh[0][1][cc] + sh[0][2][cc] + sh[0][3][cc];
    float q4 = sh[1][0][cc] + sh[1][1][cc] + sh[1][2][cc] + sh[1][3][cc];
    float m = s4 / (float)HW;
    float var = q4 / (float)HW - m * m;
    stats[(size_t)b * C + cg * 64 + cc] = make_float2(m, rsqrtf(var + 1e-5f));
  }
}

// generic apply: NHWC bf16 -> {NHWC bf16, NCHW f32} dests
__global__ __launch_bounds__(256) void inorm_apply_k(
    const bf16* __restrict__ x, const float2* __restrict__ stats, int HW, int C,
    bf16* __restrict__ dnhwc, float* __restrict__ fnchw)
{
  const int b = blockIdx.z, cg = blockIdx.y;
  const int c = cg * 64 + (threadIdx.x & 63);
  const int p = blockIdx.x * 4 + (threadIdx.x >> 6);
  const float2 st = stats[(size_t)b * C + c];
  const size_t ia = ((size_t)b * HW + p) * C + c;
  const float v = (b2f(x[ia]) - st.x) * st.y;
  if (dnhwc) dnhwc[ia] = f2b(v);
  if (fnchw) fnchw[((size_t)(b * C + c)) * HW + p] = v;
}

// ---------------------------------------------------------------------------
// Stage-2 apply: NHWC bf16 -> x-padded NCHW bf16 [b][c][128][144]
// ---------------------------------------------------------------------------
__global__ __launch_bounds__(256) void inorm_apply_pad_k(
    const bf16* __restrict__ x, const float2* __restrict__ stats,
    bf16* __restrict__ pad)
{
  const int b = blockIdx.z, cg = blockIdx.y, yy = blockIdx.x;
  const int tid = threadIdx.x;
  __shared__ bf16 t_s[64][130];
  __shared__ float2 st_s[64];
  if (tid < 64) st_s[tid] = stats[(size_t)b * 128 + cg * 64 + tid];
  __syncthreads();

  const int c8 = (tid & 7) * 8, px0 = tid >> 3;
#pragma unroll
  for (int pass = 0; pass < 4; ++pass) {
    int px = pass * 32 + px0;
    short8 v = *reinterpret_cast<const short8*>(
        reinterpret_cast<const short*>(x) +
        ((size_t)(b * 16384 + yy * 128 + px) * 128 + cg * 64 + c8));
#pragma unroll
    for (int j = 0; j < 8; ++j) {
      float2 st = st_s[c8 + j];
      t_s[c8 + j][px] = f2b((sb2f(v[j]) - st.x) * st.y);
    }
  }
  __syncthreads();

  for (int idx = tid; idx < 64 * 18; idx += 256) {
    int c = idx / 18, g = idx - (idx / 18) * 18;
    short8 v;
#pragma unroll
    for (int j = 0; j < 8; ++j) {
      int xx = g * 8 + j - 6;
      xx = xx < 0 ? 0 : (xx > 127 ? 127 : xx);
      v[j] = *reinterpret_cast<short*>(&t_s[c][xx]);
    }
    *reinterpret_cast<short8*>(
        reinterpret_cast<short*>(pad) +
        ((size_t)(b * 128 + cg * 64 + c) * 128 + yy) * 144 + g * 8) = v;
  }
}

// ---------------------------------------------------------------------------
// Correlation via MFMA banded GEMM (r11 structure, b0 batch-split).
// ---------------------------------------------------------------------------
__global__ __launch_bounds__(256) void corr_mfma_k(
    const float* __restrict__ corr, const bf16* __restrict__ pad,
    float* __restrict__ outc, bf16* __restrict__ outn, int b0)
{
  __shared__ __align__(16) char smem[26 * 64 * 16];
  short8* a_lds = reinterpret_cast<short8*>(smem);
  float* out_s = reinterpret_cast<float*>(smem);

  const int b = b0 + blockIdx.z;
  const int wg = xcd_swz(blockIdx.x, gridDim.x);
  const int y = wg >> 3, xt = wg & 7;
  const int x0 = xt * 16;
  const int tid = threadIdx.x, lane = tid & 63, wid = tid >> 6;
  const int l15 = lane & 15, lg = lane >> 4;

  for (int idx = tid; idx < 26 * 64; idx += 256) {
    short8 z = {};
    a_lds[idx] = z;
  }
  __syncthreads();

  unsigned short* ah = reinterpret_cast<unsigned short*>(a_lds);
  for (int idx = tid; idx < 169 * 16; idx += 256) {
    int t = idx >> 4, m = idx & 15;
    int dy = t / 13, dx = t - dy * 13;
    float f = corr[((size_t)b * 169 + t) * 16384 + y * 128 + x0 + m];
    bf16 hi = f2b(f);
    unsigned short hb = *reinterpret_cast<unsigned short*>(&hi);
    unsigned short lb = (unsigned short)fbits(f - b2f(hi));
    int k = m + dx;
    int ent = dy * 64 + (k >> 3) * 16 + m;
    ah[ent * 8 + (k & 7)] = hb;
    ah[(13 * 64 + ent) * 8 + (k & 7)] = lb;
  }
  __syncthreads();

  const int cg0 = wid * 2;
  f32x4 acc0 = {}, acc1 = {};
  const short* pb = reinterpret_cast<const short*>(pad);

  for (int dy = 0; dy < 13; ++dy) {
    int rowc = y + dy - 6; rowc = rowc < 0 ? 0 : (rowc > 127 ? 127 : rowc);
    short8 bhi = a_lds[dy * 64 + lane];
    short8 blo = a_lds[(13 + dy) * 64 + lane];
    size_t base0 = ((size_t)(b * 128 + cg0 * 16 + l15) * 128 + rowc) * 144
                   + x0 + lg * 8;
    short8 a0 = *reinterpret_cast<const short8*>(pb + base0);
    short8 a1 = *reinterpret_cast<const short8*>(pb + base0 + (size_t)16 * 128 * 144);
    acc0 = __builtin_amdgcn_mfma_f32_16x16x32_bf16(a0, bhi, acc0, 0, 0, 0);
    acc1 = __builtin_amdgcn_mfma_f32_16x16x32_bf16(a1, bhi, acc1, 0, 0, 0);
    acc0 = __builtin_amdgcn_mfma_f32_16x16x32_bf16(a0, blo, acc0, 0, 0, 0);
    acc1 = __builtin_amdgcn_mfma_f32_16x16x32_bf16(a1, blo, acc1, 0, 0, 0);
  }
  __syncthreads();

#pragma unroll
  for (int cgi = 0; cgi < 2; ++cgi) {
    f32x4 a = cgi ? acc1 : acc0;
    float* dst4 = out_s + l15 * 132 + (cg0 + cgi) * 16 + lg * 4;
    *reinterpret_cast<f32x4*>(dst4) = a;
  }
  __syncthreads();

  {
    int px_ = tid >> 4, c8 = (tid & 15) * 8;
    const float* row = out_s + px_ * 132 + c8;
    short8 v;
#pragma unroll
    for (int j = 0; j < 8; ++j) v[j] = fbits(row[j]);
    *reinterpret_cast<short8*>(
        reinterpret_cast<short*>(outn) +
        ((size_t)(b * 16384 + y * 128 + x0 + px_)) * 128 + c8) = v;
  }
  {
    int ch = tid >> 1, pg = tid & 1;
    float v0[4], v1[4];
#pragma unroll
    for (int i = 0; i < 4; ++i) v0[i] = out_s[(pg * 8 + i) * 132 + ch];
#pragma unroll
    for (int i = 0; i < 4; ++i) v1[i] = out_s[(pg * 8 + 4 + i) * 132 + ch];
    float* dst = outc + ((size_t)(b * 128 + ch)) * 16384 + y * 128 + x0 + pg * 8;
    *reinterpret_cast<float4*>(dst) = make_float4(v0[0], v0[1], v0[2], v0[3]);
    *reinterpret_cast<float4*>(dst + 4) = make_float4(v1[0], v1[1], v1[2], v1[3]);
  }
}

// ---------------------------------------------------------------------------
// Workspace plan — BYTES, liveness-proven. Peak 62.9 MB.
// ---------------------------------------------------------------------------
extern "C" void kernel_launch(void* const* d_in, const int* in_sizes, int n_in,
                              void* d_out, int out_size, void* d_ws, size_t ws_size,
                              hipStream_t stream) {
  const float* color = (const float*)d_in[0];
  const float* corr  = (const float*)d_in[1];
  const float* w1a = (const float*)d_in[2];  const float* b1a = (const float*)d_in[3];
  const float* w1b = (const float*)d_in[4];  const float* b1b = (const float*)d_in[5];
  const float* w2a = (const float*)d_in[6];  const float* b2a = (const float*)d_in[7];
  const float* w2b = (const float*)d_in[8];  const float* b2b = (const float*)d_in[9];
  const float* w3a = (const float*)d_in[10]; const float* b3a = (const float*)d_in[11];
  const float* w3b = (const float*)d_in[12]; const float* b3b = (const float*)d_in[13];
  const float* w4a = (const float*)d_in[14]; const float* b4a = (const float*)d_in[15];
  const float* w4b = (const float*)d_in[16]; const float* b4b = (const float*)d_in[17];

  float* out = (float*)d_out;
  char* ws = (char*)d_ws;
  const size_t MB = 1048576;
  float2* stats = (float2*)ws;
  float2* part  = (float2*)(ws + (64 << 10));
  short*  WrS   = (short*)(ws + (256 << 10));
  const short8* Wr = (const short8*)WrS;
  bf16* P0 = (bf16*)(ws + 10 * MB);
  bf16* P1 = (bf16*)(ws + 27 * MB);
  bf16* P2 = (bf16*)(ws + 44 * MB);
  float* PK = (float*)(ws + 10 * MB);
  bf16* X1 = P0;
  bf16* X2 = (bf16*)d_out;
  const float2* nost = (const float2*)nullptr;
  float* nop = (float*)nullptr;

  // ---- stage 1: conv1a -> conv1b(FM8, hi+lo) -> stats ----
  conv1a_k<<<dim3(256, 4, 4), 256, 0, stream>>>(color, X1, w1a, b1a);
  repack_k<<<36, 256, 0, stream>>>(w1b, WrS, 64, 64, 2);
  conv_mfma_k<16, 16, 0, 1><<<1024, 256, 0, stream>>>(
      X1, X2, Wr, b1b, nost, nop, 256, 256, 256, 64, 64, 16, 1);
  inorm_stats1_k<<<dim3(64, 4), 256, 0, stream>>>(X2, part, 65536, 64, 4, 64);
  inorm_stats2_k<<<dim3(1, 4), 256, 0, stream>>>(part, stats, 65536, 64, 64, 4);

  // ---- stage 2: conv2a(FM8, hi+lo) -> conv2b(FM8, hi+lo) -> pad apply ----
  repack_k<<<72, 256, 0, stream>>>(w2a, WrS, 64, 128, 2);
  conv_mfma_k<16, 16, 1, 1><<<512, 256, 0, stream>>>(
      X2, P0, Wr, b2a, stats, nop, 256, 128, 128, 64, 128, 8, 1);
  repack_k<<<144, 256, 0, stream>>>(w2b, WrS, 128, 128, 2);
  conv_mfma_k<16, 16, 0, 1><<<512, 256, 0, stream>>>(
      P0, P1, Wr, b2b, nost, nop, 128, 128, 128, 128, 128, 8, 1);
  inorm_stats1_k<<<dim3(64, 4), 256, 0, stream>>>(P1, part, 16384, 128, 4, 64);
  inorm_stats2_k<<<dim3(2, 4), 256, 0, stream>>>(part, stats, 16384, 128, 64, 4);
  inorm_apply_pad_k<<<dim3(128, 2, 4), 256, 0, stream>>>(P1, stats, P2);

  // ---- correlation (MFMA), split into 2 half-batch dispatches ----
  corr_mfma_k<<<dim3(128 * 8, 1, 2), 256, 0, stream>>>(corr, P2, out, P0, 0);
  corr_mfma_k<<<dim3(128 * 8, 1, 2), 256, 0, stream>>>(corr, P2, out, P0, 2);

  // ---- stage 3: conv3a(FM4, hi-only) -> conv3b(FM4, hi-only) -> stats ----
  repack_k<<<288, 256, 0, stream>>>(w3a, WrS, 128, 256, 1);
  conv_mfma_k<8, 16, 1, 0><<<512, 256, 0, stream>>>(
      P0, P1, Wr, b3a, nost, nop, 128, 64, 64, 128, 256, 4, 1);
  repack_k<<<576, 256, 0, stream>>>(w3b, WrS, 256, 256, 1);
  conv_mfma_k<8, 16, 0, 0><<<512, 256, 0, stream>>>(
      P1, P2, Wr, b3b, nost, nop, 64, 64, 64, 256, 256, 4, 1);
  inorm_stats1_k<<<dim3(32, 4), 256, 0, stream>>>(P2, part, 4096, 256, 4, 32);
  inorm_stats2_k<<<dim3(4, 4), 256, 0, stream>>>(part, stats, 4096, 256, 32, 4);
  inorm_apply_k<<<dim3(1024, 4, 4), 256, 0, stream>>>(
      P2, stats, 4096, 256, (bf16*)nullptr, out + 8388608);

  // ---- stage 4: conv4a/4b split-K=2, hi-only -> combine ----
  repack_k<<<1152, 256, 0, stream>>>(w4a, WrS, 256, 512, 1);
  conv_mfma_k<4, 16, 1, 0><<<1024, 256, 0, stream>>>(
      P2, (bf16*)nullptr, Wr, b4a, stats, PK, 64, 32, 32, 256, 512, 2, 2);
  combine2_k<<<2048, 256, 0, stream>>>(PK, b4a, P1, 524288, 512);
  repack_k<<<2304, 256, 0, stream>>>(w4b, WrS, 512, 512, 1);
  conv_mfma_k<4, 16, 0, 0><<<1024, 256, 0, stream>>>(
      P1, (bf16*)nullptr, Wr, b4b, nost, PK, 32, 32, 32, 512, 512, 2, 2);
  combine2_k<<<2048, 256, 0, stream>>>(PK, b4b, P2, 524288, 512);
  inorm_stats1_k<<<dim3(32, 4), 256, 0, stream>>>(P2, part, 1024, 512, 4, 32);
  inorm_stats2_k<<<dim3(8, 4), 256, 0, stream>>>(part, stats, 1024, 512, 32, 4);
  inorm_apply_k<<<dim3(256, 8, 4), 256, 0, stream>>>(
      P2, stats, 1024, 512, (bf16*)nullptr, out + 12582912);
}

// Round 22
// 421.875 us; speedup vs baseline: 1.1605x; 1.0512x over previous
//
#include <hip/hip_runtime.h>
#include <hip/hip_bf16.h>

typedef __hip_bfloat16 bf16;
typedef __attribute__((ext_vector_type(8))) short short8;
typedef __attribute__((ext_vector_type(4))) float f32x4;

__device__ __forceinline__ float b2f(bf16 v) { return __bfloat162float(v); }
__device__ __forceinline__ bf16 f2b(float v) { return __float2bfloat16(v); }
__device__ __forceinline__ short fbits(float v) {
  bf16 h = f2b(v); return *reinterpret_cast<short*>(&h);
}
__device__ __forceinline__ float sb2f(short s) {
  return b2f(*reinterpret_cast<bf16*>(&s));
}
// bijective XCD swizzle (m204): contiguous grid chunk per XCD
__device__ __forceinline__ int xcd_swz(int bid, int nwg) {
  int q = nwg >> 3, r = nwg & 7;
  int xcd = bid & 7, idx = bid >> 3;
  return (xcd < r ? xcd * (q + 1) : r * (q + 1) + (xcd - r) * q) + idx;
}

// ---------------------------------------------------------------------------
// Mega weight repack: all 7 conv layers in ONE dispatch, each into its own
// arena slice. Per-element math identical to the old per-layer repack_k.
// ---------------------------------------------------------------------------
struct RDesc {
  const float* w[7];
  int off8[7];      // short8 offset into arena
  int cin[7], cout[7];
  int base[8];      // cumulative block start, base[7] = total
};

__global__ __launch_bounds__(256) void repack_all_k(RDesc d, short* __restrict__ Wr)
{
  int blk = blockIdx.x;
  int l = 0;
  while (l < 6 && blk >= d.base[l + 1]) ++l;
  const int Cin = d.cin[l], Cout = d.cout[l];
  const int nkc = Cin >> 5, ncof = Cout >> 4;
  const size_t gid = (size_t)(blk - d.base[l]) * 256 + threadIdx.x;
  const int lane = gid & 63;
  size_t r = gid >> 6;
  const int tap = r % 9; r /= 9;
  const int kcc = r % nkc; r /= nkc;
  const int cof = r % ncof;
  const int hl = r / ncof;
  const float* w = d.w[l];
  const int co = cof * 16 + (lane & 15);
  short8 v;
#pragma unroll
  for (int j = 0; j < 8; ++j) {
    int ci = kcc * 32 + ((lane >> 4) * 8 + j);
    float wv = w[((size_t)co * Cin + ci) * 9 + tap];
    bf16 hi = f2b(wv);
    v[j] = hl ? fbits(wv - b2f(hi)) : *reinterpret_cast<short*>(&hi);
  }
  *reinterpret_cast<short8*>(Wr + ((size_t)d.off8[l] + gid) * 8) = v;
}

// ---------------------------------------------------------------------------
// MFMA implicit-GEMM 3x3 conv, per-layer tile FM = R*CX/32, cog-major 1D
// grid + XCD swizzle, optional split-K (KS), optional fused inorm (stats).
// LO=1: hi+lo weight pair (f32-precision); LO=0: hi only.
// S=1: conv on the SUBSAMPLED image (subsample-then-pad-conv).
// ---------------------------------------------------------------------------
template<int R, int CX, int S, int LO>
__global__ __launch_bounds__(256) void conv_mfma_k(
    const bf16* __restrict__ src, bf16* __restrict__ dst,
    const short8* __restrict__ Wr, const float* __restrict__ bias,
    const float2* __restrict__ stats, float* __restrict__ pout,
    int Win, int Hout, int Wout, int Cin, int Cout, int XT, int KS)
{
  constexpr int ROWS = R + 2;
  constexpr int COLS = CX + 2;
  constexpr int NGR = ROWS * 4 * COLS;
  constexpr int FM = (R * CX) / 32;
  __shared__ short8 a_s[NGR];

  const int ytn = Hout / R;
  const int nxy = XT * ytn;
  const int ncog = Cout >> 6;
  const int wg = xcd_swz(blockIdx.x, gridDim.x);
  const int ks = wg / (ncog * 4 * nxy);
  const int rem2 = wg - ks * (ncog * 4 * nxy);
  const int cog = rem2 / (4 * nxy);
  const int rem = rem2 - cog * (4 * nxy);
  const int b = rem / nxy;
  const int pxb = rem - b * nxy;
  const int xt = pxb % XT, yt = pxb / XT;
  const int x0 = xt * CX, y0 = yt * R;

  const int tid = threadIdx.x, lane = tid & 63, wid = tid >> 6;
  const int wm = wid & 1, wn = wid >> 1;
  const int nkc = Cin >> 5;
  const int nkcs = nkc / KS;
  const int kc0 = ks * nkcs;
  const int ncof = Cout >> 4;
  const int l15 = lane & 15, lg = lane >> 4;

  f32x4 acc[FM][2] = {};

  int arow[FM], acolb[FM];
#pragma unroll
  for (int fm = 0; fm < FM; ++fm) {
    int p = wm * (R * CX / 2) + fm * 16 + l15;
    arow[fm] = p / CX;
    acolb[fm] = p % CX;
  }

  auto bload = [&](int hl, int fn, int kcc, int tap) -> short8 {
    int cof = cog * 4 + wn * 2 + fn;
    return Wr[((((size_t)hl * ncof + cof) * nkc + kcc) * 9 + tap) * 64 + lane];
  };

  short8 bc[2][2], bn_[2][2];
  bc[0][0] = bload(0, 0, kc0, 0); bc[0][1] = bload(0, 1, kc0, 0);
  if (LO) { bc[1][0] = bload(1, 0, kc0, 0); bc[1][1] = bload(1, 1, kc0, 0); }

  for (int kc = kc0; kc < kc0 + nkcs; ++kc) {
    __syncthreads();
    for (int idx = tid; idx < NGR; idx += 256) {
      int g = idx & 3, cix = idx >> 2;
      int col = cix % COLS, row = cix / COLS;
      int sy = y0 + row - 1;
      int sx = x0 + col - 1;
      short8 v = {};
      if (sy >= 0 && sy < Hout && sx >= 0 && sx < Wout) {
        int ry = S ? 2 * sy : sy, rx = S ? 2 * sx : sx;
        v = *reinterpret_cast<const short8*>(
            reinterpret_cast<const short*>(src) +
            (((size_t)b * (S ? 2 * Hout : Hout) + ry) * Win + rx) * Cin +
            kc * 32 + g * 8);
        if (stats) {                     // fused inorm apply (bit-exact)
          const float2* st = stats + (size_t)b * Cin + kc * 32 + g * 8;
#pragma unroll
          for (int j = 0; j < 8; ++j)
            v[j] = fbits((sb2f(v[j]) - st[j].x) * st[j].y);
        }
      }
      a_s[(row * 4 + g) * COLS + col] = v;
    }
    __syncthreads();

#pragma unroll
    for (int tap = 0; tap < 9; ++tap) {
      const int dy = tap / 3, dx = tap % 3;
      int nt = tap + 1, nk = kc;
      if (nt == 9) { nt = 0; nk = (kc + 1 < kc0 + nkcs) ? kc + 1 : kc0; }
      bn_[0][0] = bload(0, 0, nk, nt); bn_[0][1] = bload(0, 1, nk, nt);
      if (LO) { bn_[1][0] = bload(1, 0, nk, nt); bn_[1][1] = bload(1, 1, nk, nt); }
#pragma unroll
      for (int fm = 0; fm < FM; ++fm) {
        short8 a = a_s[((arow[fm] + dy) * 4 + lg) * COLS + acolb[fm] + dx];
        acc[fm][0] = __builtin_amdgcn_mfma_f32_16x16x32_bf16(a, bc[0][0], acc[fm][0], 0, 0, 0);
        if (LO)
          acc[fm][0] = __builtin_amdgcn_mfma_f32_16x16x32_bf16(a, bc[1][0], acc[fm][0], 0, 0, 0);
        acc[fm][1] = __builtin_amdgcn_mfma_f32_16x16x32_bf16(a, bc[0][1], acc[fm][1], 0, 0, 0);
        if (LO)
          acc[fm][1] = __builtin_amdgcn_mfma_f32_16x16x32_bf16(a, bc[1][1], acc[fm][1], 0, 0, 0);
      }
      bc[0][0] = bn_[0][0]; bc[0][1] = bn_[0][1];
      if (LO) { bc[1][0] = bn_[1][0]; bc[1][1] = bn_[1][1]; }
    }
  }

#pragma unroll
  for (int fn = 0; fn < 2; ++fn) {
    int co = cog * 64 + wn * 32 + fn * 16 + l15;
    float bs = bias[co];
#pragma unroll
    for (int fm = 0; fm < FM; ++fm) {
#pragma unroll
      for (int j = 0; j < 4; ++j) {
        int p = wm * (R * CX / 2) + fm * 16 + lg * 4 + j;
        int r = p / CX, x = p % CX;
        size_t oi = ((size_t)(b * Hout + y0 + r) * Wout + x0 + x) * Cout + co;
        if (pout) {
          pout[(size_t)ks * ((size_t)4 * Hout * Wout * Cout) + oi] = acc[fm][fn][j];
        } else {
          dst[oi] = f2b(fmaxf(acc[fm][fn][j] + bs, 0.f));
        }
      }
    }
  }
}

// combine 2 split-K partials: dst = bf16(relu(p0 + p1 + bias)), NHWC.
__global__ __launch_bounds__(256) void combine2_k(
    const float* __restrict__ p, const float* __restrict__ bias,
    bf16* __restrict__ dst, int n4, int Cout)
{
  int i = blockIdx.x * 256 + threadIdx.x;
  if (i >= n4) return;
  float4 a = reinterpret_cast<const float4*>(p)[i];
  float4 c = reinterpret_cast<const float4*>(p + (size_t)n4 * 4)[i];
  int co = (i * 4) & (Cout - 1);
  float4 bs = *reinterpret_cast<const float4*>(bias + co);
  short v0 = fbits(fmaxf(a.x + c.x + bs.x, 0.f));
  short v1 = fbits(fmaxf(a.y + c.y + bs.y, 0.f));
  short v2 = fbits(fmaxf(a.z + c.z + bs.z, 0.f));
  short v3 = fbits(fmaxf(a.w + c.w + bs.w, 0.f));
  short4 pk = make_short4(v0, v1, v2, v3);
  *reinterpret_cast<short4*>(reinterpret_cast<short*>(dst) + (size_t)i * 4) = pk;
}

// ---------------------------------------------------------------------------
// conv1a: Cin=2 VALU direct conv. NCHW f32 color (subsample-then-conv),
// NHWC bf16 out, bias+ReLU.
// ---------------------------------------------------------------------------
__global__ __launch_bounds__(256) void conv1a_k(
    const float* __restrict__ src, bf16* __restrict__ dst,
    const float* __restrict__ w, const float* __restrict__ bias)
{
  const int b = blockIdx.z, cog = blockIdx.y;
  const int ty0 = (blockIdx.x / 16) * 16, tx0 = (blockIdx.x % 16) * 16;
  const int tid = threadIdx.x, tx = tid & 15, ty = tid >> 4;

  __shared__ float in_s[2][18][18];
  __shared__ __align__(16) float w_s[2][3][3][16];

  for (int idx = tid; idx < 2 * 324; idx += 256) {
    int ci = idx / 324, r = idx - ci * 324;
    int iy = r / 18, ix = r - iy * 18;
    int gy = ty0 + iy - 1, gx = tx0 + ix - 1;
    float v = 0.f;
    if (gy >= 0 && gy < 256 && gx >= 0 && gx < 256)
      v = src[((size_t)(b * 2 + ci) * 512 + 2 * gy) * 512 + 2 * gx];
    in_s[ci][iy][ix] = v;
  }
  for (int idx = tid; idx < 2 * 144; idx += 256) {
    int co = idx & 15, r = idx >> 4;
    int ci = r / 9, k = r - ci * 9;
    w_s[ci][k / 3][k % 3][co] = w[(size_t)((cog * 16 + co) * 2 + ci) * 9 + k];
  }
  __syncthreads();

  float acc[16];
#pragma unroll
  for (int i = 0; i < 16; ++i) acc[i] = 0.f;
  for (int ci = 0; ci < 2; ++ci)
#pragma unroll
    for (int dy = 0; dy < 3; ++dy)
#pragma unroll
      for (int dx = 0; dx < 3; ++dx) {
        float v = in_s[ci][ty + dy][tx + dx];
        const float4* wv = (const float4*)(&w_s[ci][dy][dx][0]);
        float4 w0 = wv[0], w1 = wv[1], w2 = wv[2], w3 = wv[3];
        acc[0] = fmaf(v, w0.x, acc[0]);   acc[1] = fmaf(v, w0.y, acc[1]);
        acc[2] = fmaf(v, w0.z, acc[2]);   acc[3] = fmaf(v, w0.w, acc[3]);
        acc[4] = fmaf(v, w1.x, acc[4]);   acc[5] = fmaf(v, w1.y, acc[5]);
        acc[6] = fmaf(v, w1.z, acc[6]);   acc[7] = fmaf(v, w1.w, acc[7]);
        acc[8] = fmaf(v, w2.x, acc[8]);   acc[9] = fmaf(v, w2.y, acc[9]);
        acc[10] = fmaf(v, w2.z, acc[10]); acc[11] = fmaf(v, w2.w, acc[11]);
        acc[12] = fmaf(v, w3.x, acc[12]); acc[13] = fmaf(v, w3.y, acc[13]);
        acc[14] = fmaf(v, w3.z, acc[14]); acc[15] = fmaf(v, w3.w, acc[15]);
      }

  const int gy = ty0 + ty, gx = tx0 + tx;
  short8 s0, s1;
#pragma unroll
  for (int j = 0; j < 8; ++j) {
    s0[j] = fbits(fmaxf(acc[j] + bias[cog * 16 + j], 0.f));
    s1[j] = fbits(fmaxf(acc[8 + j] + bias[cog * 16 + 8 + j], 0.f));
  }
  short8* dp = reinterpret_cast<short8*>(
      reinterpret_cast<short*>(dst) + (((size_t)(b * 256 + gy) * 256 + gx) * 64 + cog * 16));
  dp[0] = s0; dp[1] = s1;
}

// ---------------------------------------------------------------------------
// InstanceNorm stats, 2-level (r17 vectorized stats1).
// ---------------------------------------------------------------------------
__global__ __launch_bounds__(256) void inorm_stats1_k(
    const bf16* __restrict__ x, float2* __restrict__ part,
    int HW, int C, int nb, int PC)
{
  const int b = blockIdx.y, pc = blockIdx.x;
  const int NC8 = C >> 3;
  const int pgc = 256 / NC8;
  const int c8 = (threadIdx.x % NC8) * 8;
  const int pg = threadIdx.x / NC8;
  const int chunk = HW / PC;
  const int p0 = pc * chunk;

  float s[8] = {}, ss[8] = {};
  for (int p = p0 + pg; p < p0 + chunk; p += pgc) {
    short8 v = *reinterpret_cast<const short8*>(
        reinterpret_cast<const short*>(x) + ((size_t)b * HW + p) * C + c8);
#pragma unroll
    for (int j = 0; j < 8; ++j) {
      float f = sb2f(v[j]);
      s[j] += f; ss[j] += f * f;
    }
  }
  __shared__ float sh[2][2048];
#pragma unroll
  for (int j = 0; j < 8; ++j) {
    sh[0][pg * C + c8 + j] = s[j];
    sh[1][pg * C + c8 + j] = ss[j];
  }
  __syncthreads();
  for (int c = threadIdx.x; c < C; c += 256) {
    float as = 0.f, aq = 0.f;
    for (int g = 0; g < pgc; ++g) { as += sh[0][g * C + c]; aq += sh[1][g * C + c]; }
    part[((size_t)pc * nb + b) * C + c] = make_float2(as, aq);
  }
}

__global__ __launch_bounds__(256) void inorm_stats2_k(
    const float2* __restrict__ part, float2* __restrict__ stats,
    int HW, int C, int PC, int nb)
{
  const int b = blockIdx.y, cg = blockIdx.x;
  const int c = threadIdx.x & 63, i = threadIdx.x >> 6;
  float s = 0.f, ss = 0.f;
  for (int pc = i; pc < PC; pc += 4) {
    float2 v = part[((size_t)pc * nb + b) * C + cg * 64 + c];
    s += v.x; ss += v.y;
  }
  __shared__ float sh[2][4][64];
  sh[0][i][c] = s; sh[1][i][c] = ss;
  __syncthreads();
  if (threadIdx.x < 64) {
    int cc = threadIdx.x;
    float s4 = sh[0][0][cc] + sh[0][1][cc] + sh[0][2][cc] + sh[0][3][cc];
    float q4 = sh[1][0][cc] + sh[1][1][cc] + sh[1][2][cc] + sh[1][3][cc];
    float m = s4 / (float)HW;
    float var = q4 / (float)HW - m * m;
    stats[(size_t)b * C + cg * 64 + cc] = make_float2(m, rsqrtf(var + 1e-5f));
  }
}

// generic apply: NHWC bf16 -> {NHWC bf16, NCHW f32} dests
__global__ __launch_bounds__(256) void inorm_apply_k(
    const bf16* __restrict__ x, const float2* __restrict__ stats, int HW, int C,
    bf16* __restrict__ dnhwc, float* __restrict__ fnchw)
{
  const int b = blockIdx.z, cg = blockIdx.y;
  const int c = cg * 64 + (threadIdx.x & 63);
  const int p = blockIdx.x * 4 + (threadIdx.x >> 6);
  const float2 st = stats[(size_t)b * C + c];
  const size_t ia = ((size_t)b * HW + p) * C + c;
  const float v = (b2f(x[ia]) - st.x) * st.y;
  if (dnhwc) dnhwc[ia] = f2b(v);
  if (fnchw) fnchw[((size_t)(b * C + c)) * HW + p] = v;
}

// ---------------------------------------------------------------------------
// Stage-2 apply: NHWC bf16 -> x-padded NCHW bf16 [b][c][128][144]
// ---------------------------------------------------------------------------
__global__ __launch_bounds__(256) void inorm_apply_pad_k(
    const bf16* __restrict__ x, const float2* __restrict__ stats,
    bf16* __restrict__ pad)
{
  const int b = blockIdx.z, cg = blockIdx.y, yy = blockIdx.x;
  const int tid = threadIdx.x;
  __shared__ bf16 t_s[64][130];
  __shared__ float2 st_s[64];
  if (tid < 64) st_s[tid] = stats[(size_t)b * 128 + cg * 64 + tid];
  __syncthreads();

  const int c8 = (tid & 7) * 8, px0 = tid >> 3;
#pragma unroll
  for (int pass = 0; pass < 4; ++pass) {
    int px = pass * 32 + px0;
    short8 v = *reinterpret_cast<const short8*>(
        reinterpret_cast<const short*>(x) +
        ((size_t)(b * 16384 + yy * 128 + px) * 128 + cg * 64 + c8));
#pragma unroll
    for (int j = 0; j < 8; ++j) {
      float2 st = st_s[c8 + j];
      t_s[c8 + j][px] = f2b((sb2f(v[j]) - st.x) * st.y);
    }
  }
  __syncthreads();

  for (int idx = tid; idx < 64 * 18; idx += 256) {
    int c = idx / 18, g = idx - (idx / 18) * 18;
    short8 v;
#pragma unroll
    for (int j = 0; j < 8; ++j) {
      int xx = g * 8 + j - 6;
      xx = xx < 0 ? 0 : (xx > 127 ? 127 : xx);
      v[j] = *reinterpret_cast<short*>(&t_s[c][xx]);
    }
    *reinterpret_cast<short8*>(
        reinterpret_cast<short*>(pad) +
        ((size_t)(b * 128 + cg * 64 + c) * 128 + yy) * 144 + g * 8) = v;
  }
}

// ---------------------------------------------------------------------------
// Correlation via MFMA banded GEMM (r11 structure).
// ---------------------------------------------------------------------------
__global__ __launch_bounds__(256) void corr_mfma_k(
    const float* __restrict__ corr, const bf16* __restrict__ pad,
    float* __restrict__ outc, bf16* __restrict__ outn, int b0)
{
  __shared__ __align__(16) char smem[26 * 64 * 16];
  short8* a_lds = reinterpret_cast<short8*>(smem);
  float* out_s = reinterpret_cast<float*>(smem);

  const int b = b0 + blockIdx.z;
  const int wg = xcd_swz(blockIdx.x, gridDim.x);
  const int y = wg >> 3, xt = wg & 7;
  const int x0 = xt * 16;
  const int tid = threadIdx.x, lane = tid & 63, wid = tid >> 6;
  const int l15 = lane & 15, lg = lane >> 4;

  for (int idx = tid; idx < 26 * 64; idx += 256) {
    short8 z = {};
    a_lds[idx] = z;
  }
  __syncthreads();

  unsigned short* ah = reinterpret_cast<unsigned short*>(a_lds);
  for (int idx = tid; idx < 169 * 16; idx += 256) {
    int t = idx >> 4, m = idx & 15;
    int dy = t / 13, dx = t - dy * 13;
    float f = corr[((size_t)b * 169 + t) * 16384 + y * 128 + x0 + m];
    bf16 hi = f2b(f);
    unsigned short hb = *reinterpret_cast<unsigned short*>(&hi);
    unsigned short lb = (unsigned short)fbits(f - b2f(hi));
    int k = m + dx;
    int ent = dy * 64 + (k >> 3) * 16 + m;
    ah[ent * 8 + (k & 7)] = hb;
    ah[(13 * 64 + ent) * 8 + (k & 7)] = lb;
  }
  __syncthreads();

  const int cg0 = wid * 2;
  f32x4 acc0 = {}, acc1 = {};
  const short* pb = reinterpret_cast<const short*>(pad);

  for (int dy = 0; dy < 13; ++dy) {
    int rowc = y + dy - 6; rowc = rowc < 0 ? 0 : (rowc > 127 ? 127 : rowc);
    short8 bhi = a_lds[dy * 64 + lane];
    short8 blo = a_lds[(13 + dy) * 64 + lane];
    size_t base0 = ((size_t)(b * 128 + cg0 * 16 + l15) * 128 + rowc) * 144
                   + x0 + lg * 8;
    short8 a0 = *reinterpret_cast<const short8*>(pb + base0);
    short8 a1 = *reinterpret_cast<const short8*>(pb + base0 + (size_t)16 * 128 * 144);
    acc0 = __builtin_amdgcn_mfma_f32_16x16x32_bf16(a0, bhi, acc0, 0, 0, 0);
    acc1 = __builtin_amdgcn_mfma_f32_16x16x32_bf16(a1, bhi, acc1, 0, 0, 0);
    acc0 = __builtin_amdgcn_mfma_f32_16x16x32_bf16(a0, blo, acc0, 0, 0, 0);
    acc1 = __builtin_amdgcn_mfma_f32_16x16x32_bf16(a1, blo, acc1, 0, 0, 0);
  }
  __syncthreads();

#pragma unroll
  for (int cgi = 0; cgi < 2; ++cgi) {
    f32x4 a = cgi ? acc1 : acc0;
    float* dst4 = out_s + l15 * 132 + (cg0 + cgi) * 16 + lg * 4;
    *reinterpret_cast<f32x4*>(dst4) = a;
  }
  __syncthreads();

  {
    int px_ = tid >> 4, c8 = (tid & 15) * 8;
    const float* row = out_s + px_ * 132 + c8;
    short8 v;
#pragma unroll
    for (int j = 0; j < 8; ++j) v[j] = fbits(row[j]);
    *reinterpret_cast<short8*>(
        reinterpret_cast<short*>(outn) +
        ((size_t)(b * 16384 + y * 128 + x0 + px_)) * 128 + c8) = v;
  }
  {
    int ch = tid >> 1, pg = tid & 1;
    float v0[4], v1[4];
#pragma unroll
    for (int i = 0; i < 4; ++i) v0[i] = out_s[(pg * 8 + i) * 132 + ch];
#pragma unroll
    for (int i = 0; i < 4; ++i) v1[i] = out_s[(pg * 8 + 4 + i) * 132 + ch];
    float* dst = outc + ((size_t)(b * 128 + ch)) * 16384 + y * 128 + x0 + pg * 8;
    *reinterpret_cast<float4*>(dst) = make_float4(v0[0], v0[1], v0[2], v0[3]);
    *reinterpret_cast<float4*>(dst + 4) = make_float4(v1[0], v1[1], v1[2], v1[3]);
  }
}

// ---------------------------------------------------------------------------
// Workspace plan — BYTES, liveness-proven. Peak ~63.1 MB (< 67.17 proven).
//   stats @ 0 (16 KB); Wr arena @ 64 KB (9.42 MB, ends 9.95 MB < P0@10MB);
//   P0 @ 10 MB, P1 @ 27 MB, P2 @ 44 MB (pad 18.87 MB, ends 62.87 MB);
//   part @ 63 MB (128 KB). PK = P0 during stage 4. X2 = d_out scratch.
// ---------------------------------------------------------------------------
extern "C" void kernel_launch(void* const* d_in, const int* in_sizes, int n_in,
                              void* d_out, int out_size, void* d_ws, size_t ws_size,
                              hipStream_t stream) {
  const float* color = (const float*)d_in[0];
  const float* corr  = (const float*)d_in[1];
  const float* w1a = (const float*)d_in[2];  const float* b1a = (const float*)d_in[3];
  const float* w1b = (const float*)d_in[4];  const float* b1b = (const float*)d_in[5];
  const float* w2a = (const float*)d_in[6];  const float* b2a = (const float*)d_in[7];
  const float* w2b = (const float*)d_in[8];  const float* b2b = (const float*)d_in[9];
  const float* w3a = (const float*)d_in[10]; const float* b3a = (const float*)d_in[11];
  const float* w3b = (const float*)d_in[12]; const float* b3b = (const float*)d_in[13];
  const float* w4a = (const float*)d_in[14]; const float* b4a = (const float*)d_in[15];
  const float* w4b = (const float*)d_in[16]; const float* b4b = (const float*)d_in[17];

  float* out = (float*)d_out;
  char* ws = (char*)d_ws;
  const size_t MB = 1048576;
  float2* stats = (float2*)ws;
  short*  WrS   = (short*)(ws + (64 << 10));
  float2* part  = (float2*)(ws + 63 * MB);
  bf16* P0 = (bf16*)(ws + 10 * MB);
  bf16* P1 = (bf16*)(ws + 27 * MB);
  bf16* P2 = (bf16*)(ws + 44 * MB);
  float* PK = (float*)(ws + 10 * MB);
  bf16* X1 = P0;
  bf16* X2 = (bf16*)d_out;
  const float2* nost = (const float2*)nullptr;
  float* nop = (float*)nullptr;

  // per-layer arena offsets (short8 units) and cumulative block bases
  // sizes: w1b 9216, w2a 18432, w2b 36864, w3a 36864, w3b 73728,
  //        w4a 147456, w4b 294912 (blocks = size/256)
  RDesc rd;
  rd.w[0] = w1b; rd.w[1] = w2a; rd.w[2] = w2b; rd.w[3] = w3a;
  rd.w[4] = w3b; rd.w[5] = w4a; rd.w[6] = w4b;
  const int off8[7]  = {0, 9216, 27648, 64512, 101376, 175104, 322560};
  const int cin_[7]  = {64, 64, 128, 128, 256, 256, 512};
  const int cout_[7] = {64, 128, 128, 256, 256, 512, 512};
  // nhl: layers 0-2 hi+lo (the gid range covers hl=0..1 because their
  // arena size includes both); layers 3-6 hi-only (gid range = hl=0 only)
  int bases[8]; bases[0] = 0;
  const int nblk[7] = {36, 72, 144, 144, 288, 576, 1152};
  for (int i = 0; i < 7; ++i) { rd.off8[i] = off8[i]; rd.cin[i] = cin_[i];
    rd.cout[i] = cout_[i]; bases[i + 1] = bases[i] + nblk[i]; }
  for (int i = 0; i < 8; ++i) rd.base[i] = bases[i];
  const short8* WrV = (const short8*)WrS;

  // ---- ALL weight repacks in one dispatch (no deps on activations) ----
  repack_all_k<<<bases[7], 256, 0, stream>>>(rd, WrS);

  // ---- stage 1: conv1a -> conv1b(FM8, hi+lo) -> stats ----
  conv1a_k<<<dim3(256, 4, 4), 256, 0, stream>>>(color, X1, w1a, b1a);
  conv_mfma_k<16, 16, 0, 1><<<1024, 256, 0, stream>>>(
      X1, X2, WrV + off8[0], b1b, nost, nop, 256, 256, 256, 64, 64, 16, 1);
  inorm_stats1_k<<<dim3(64, 4), 256, 0, stream>>>(X2, part, 65536, 64, 4, 64);
  inorm_stats2_k<<<dim3(1, 4), 256, 0, stream>>>(part, stats, 65536, 64, 64, 4);

  // ---- stage 2: conv2a(FM8, hi+lo, fused inorm) -> conv2b -> pad apply ----
  conv_mfma_k<16, 16, 1, 1><<<512, 256, 0, stream>>>(
      X2, P0, WrV + off8[1], b2a, stats, nop, 256, 128, 128, 64, 128, 8, 1);
  conv_mfma_k<16, 16, 0, 1><<<512, 256, 0, stream>>>(
      P0, P1, WrV + off8[2], b2b, nost, nop, 128, 128, 128, 128, 128, 8, 1);
  inorm_stats1_k<<<dim3(64, 4), 256, 0, stream>>>(P1, part, 16384, 128, 4, 64);
  inorm_stats2_k<<<dim3(2, 4), 256, 0, stream>>>(part, stats, 16384, 128, 64, 4);
  inorm_apply_pad_k<<<dim3(128, 2, 4), 256, 0, stream>>>(P1, stats, P2);

  // ---- correlation (MFMA), single dispatch ----
  corr_mfma_k<<<dim3(128 * 8, 1, 4), 256, 0, stream>>>(corr, P2, out, P0, 0);

  // ---- stage 3: conv3a(FM4, hi) -> conv3b(FM4, hi) -> stats; apply f32 ----
  conv_mfma_k<8, 16, 1, 0><<<512, 256, 0, stream>>>(
      P0, P1, WrV + off8[3], b3a, nost, nop, 128, 64, 64, 128, 256, 4, 1);
  conv_mfma_k<8, 16, 0, 0><<<512, 256, 0, stream>>>(
      P1, P2, WrV + off8[4], b3b, nost, nop, 64, 64, 64, 256, 256, 4, 1);
  inorm_stats1_k<<<dim3(32, 4), 256, 0, stream>>>(P2, part, 4096, 256, 4, 32);
  inorm_stats2_k<<<dim3(4, 4), 256, 0, stream>>>(part, stats, 4096, 256, 32, 4);
  inorm_apply_k<<<dim3(1024, 4, 4), 256, 0, stream>>>(
      P2, stats, 4096, 256, (bf16*)nullptr, out + 8388608);

  // ---- stage 4: conv4a/4b split-K=2, hi-only -> combine ----
  conv_mfma_k<4, 16, 1, 0><<<1024, 256, 0, stream>>>(
      P2, (bf16*)nullptr, WrV + off8[5], b4a, stats, PK, 64, 32, 32, 256, 512, 2, 2);
  combine2_k<<<2048, 256, 0, stream>>>(PK, b4a, P1, 524288, 512);
  conv_mfma_k<4, 16, 0, 0><<<1024, 256, 0, stream>>>(
      P1, (bf16*)nullptr, WrV + off8[6], b4b, nost, PK, 32, 32, 32, 512, 512, 2, 2);
  combine2_k<<<2048, 256, 0, stream>>>(PK, b4b, P2, 524288, 512);
  inorm_stats1_k<<<dim3(32, 4), 256, 0, stream>>>(P2, part, 1024, 512, 4, 32);
  inorm_stats2_k<<<dim3(8, 4), 256, 0, stream>>>(part, stats, 1024, 512, 32, 4);
  inorm_apply_k<<<dim3(256, 8, 4), 256, 0, stream>>>(
      P2, stats, 1024, 512, (bf16*)nullptr, out + 12582912);
}

// Round 23
// 420.713 us; speedup vs baseline: 1.1637x; 1.0028x over previous
//
#include <hip/hip_runtime.h>
#include <hip/hip_bf16.h>

typedef __hip_bfloat16 bf16;
typedef __attribute__((ext_vector_type(8))) short short8;
typedef __attribute__((ext_vector_type(4))) float f32x4;

__device__ __forceinline__ float b2f(bf16 v) { return __bfloat162float(v); }
__device__ __forceinline__ bf16 f2b(float v) { return __float2bfloat16(v); }
__device__ __forceinline__ short fbits(float v) {
  bf16 h = f2b(v); return *reinterpret_cast<short*>(&h);
}
__device__ __forceinline__ float sb2f(short s) {
  return b2f(*reinterpret_cast<bf16*>(&s));
}
// bijective XCD swizzle (m204): contiguous grid chunk per XCD
__device__ __forceinline__ int xcd_swz(int bid, int nwg) {
  int q = nwg >> 3, r = nwg & 7;
  int xcd = bid & 7, idx = bid >> 3;
  return (xcd < r ? xcd * (q + 1) : r * (q + 1) + (xcd - r) * q) + idx;
}

// ---------------------------------------------------------------------------
// Mega weight repack: all 7 conv layers in ONE dispatch.
// ---------------------------------------------------------------------------
struct RDesc {
  const float* w[7];
  int off8[7];
  int cin[7], cout[7];
  int base[8];
};

__global__ __launch_bounds__(256) void repack_all_k(RDesc d, short* __restrict__ Wr)
{
  int blk = blockIdx.x;
  int l = 0;
  while (l < 6 && blk >= d.base[l + 1]) ++l;
  const int Cin = d.cin[l], Cout = d.cout[l];
  const int nkc = Cin >> 5, ncof = Cout >> 4;
  const size_t gid = (size_t)(blk - d.base[l]) * 256 + threadIdx.x;
  const int lane = gid & 63;
  size_t r = gid >> 6;
  const int tap = r % 9; r /= 9;
  const int kcc = r % nkc; r /= nkc;
  const int cof = r % ncof;
  const int hl = r / ncof;
  const float* w = d.w[l];
  const int co = cof * 16 + (lane & 15);
  short8 v;
#pragma unroll
  for (int j = 0; j < 8; ++j) {
    int ci = kcc * 32 + ((lane >> 4) * 8 + j);
    float wv = w[((size_t)co * Cin + ci) * 9 + tap];
    bf16 hi = f2b(wv);
    v[j] = hl ? fbits(wv - b2f(hi)) : *reinterpret_cast<short*>(&hi);
  }
  *reinterpret_cast<short8*>(Wr + ((size_t)d.off8[l] + gid) * 8) = v;
}

// ---------------------------------------------------------------------------
// MFMA implicit-GEMM 3x3 conv. LO=1: hi+lo issued in fm-PAIRS (4 hi then
// 4 lo; dependent same-acc MFMAs 4 apart instead of adjacent; per-acc
// hi->lo order per tap unchanged -> bit-exact). Otherwise r22 structure.
// ---------------------------------------------------------------------------
template<int R, int CX, int S, int LO>
__global__ __launch_bounds__(256) void conv_mfma_k(
    const bf16* __restrict__ src, bf16* __restrict__ dst,
    const short8* __restrict__ Wr, const float* __restrict__ bias,
    const float2* __restrict__ stats, float* __restrict__ pout,
    int Win, int Hout, int Wout, int Cin, int Cout, int XT, int KS)
{
  constexpr int ROWS = R + 2;
  constexpr int COLS = CX + 2;
  constexpr int NGR = ROWS * 4 * COLS;
  constexpr int FM = (R * CX) / 32;
  __shared__ short8 a_s[NGR];

  const int ytn = Hout / R;
  const int nxy = XT * ytn;
  const int ncog = Cout >> 6;
  const int wg = xcd_swz(blockIdx.x, gridDim.x);
  const int ks = wg / (ncog * 4 * nxy);
  const int rem2 = wg - ks * (ncog * 4 * nxy);
  const int cog = rem2 / (4 * nxy);
  const int rem = rem2 - cog * (4 * nxy);
  const int b = rem / nxy;
  const int pxb = rem - b * nxy;
  const int xt = pxb % XT, yt = pxb / XT;
  const int x0 = xt * CX, y0 = yt * R;

  const int tid = threadIdx.x, lane = tid & 63, wid = tid >> 6;
  const int wm = wid & 1, wn = wid >> 1;
  const int nkc = Cin >> 5;
  const int nkcs = nkc / KS;
  const int kc0 = ks * nkcs;
  const int ncof = Cout >> 4;
  const int l15 = lane & 15, lg = lane >> 4;

  f32x4 acc[FM][2] = {};

  int arow[FM], acolb[FM];
#pragma unroll
  for (int fm = 0; fm < FM; ++fm) {
    int p = wm * (R * CX / 2) + fm * 16 + l15;
    arow[fm] = p / CX;
    acolb[fm] = p % CX;
  }

  auto bload = [&](int hl, int fn, int kcc, int tap) -> short8 {
    int cof = cog * 4 + wn * 2 + fn;
    return Wr[((((size_t)hl * ncof + cof) * nkc + kcc) * 9 + tap) * 64 + lane];
  };

  short8 bc[2][2], bn_[2][2];
  bc[0][0] = bload(0, 0, kc0, 0); bc[0][1] = bload(0, 1, kc0, 0);
  if (LO) { bc[1][0] = bload(1, 0, kc0, 0); bc[1][1] = bload(1, 1, kc0, 0); }

  for (int kc = kc0; kc < kc0 + nkcs; ++kc) {
    __syncthreads();
    for (int idx = tid; idx < NGR; idx += 256) {
      int g = idx & 3, cix = idx >> 2;
      int col = cix % COLS, row = cix / COLS;
      int sy = y0 + row - 1;
      int sx = x0 + col - 1;
      short8 v = {};
      if (sy >= 0 && sy < Hout && sx >= 0 && sx < Wout) {
        int ry = S ? 2 * sy : sy, rx = S ? 2 * sx : sx;
        v = *reinterpret_cast<const short8*>(
            reinterpret_cast<const short*>(src) +
            (((size_t)b * (S ? 2 * Hout : Hout) + ry) * Win + rx) * Cin +
            kc * 32 + g * 8);
        if (stats) {                     // fused inorm apply (bit-exact)
          const float2* st = stats + (size_t)b * Cin + kc * 32 + g * 8;
#pragma unroll
          for (int j = 0; j < 8; ++j)
            v[j] = fbits((sb2f(v[j]) - st[j].x) * st[j].y);
        }
      }
      a_s[(row * 4 + g) * COLS + col] = v;
    }
    __syncthreads();

#pragma unroll
    for (int tap = 0; tap < 9; ++tap) {
      const int dy = tap / 3, dx = tap % 3;
      int nt = tap + 1, nk = kc;
      if (nt == 9) { nt = 0; nk = (kc + 1 < kc0 + nkcs) ? kc + 1 : kc0; }
      bn_[0][0] = bload(0, 0, nk, nt); bn_[0][1] = bload(0, 1, nk, nt);
      if (LO) { bn_[1][0] = bload(1, 0, nk, nt); bn_[1][1] = bload(1, 1, nk, nt); }
      if (LO) {
        // fm-pairs: 4 hi MFMAs then 4 lo -> dependent pairs 4 apart
#pragma unroll
        for (int fm = 0; fm < FM; fm += 2) {
          short8 a0 = a_s[((arow[fm] + dy) * 4 + lg) * COLS + acolb[fm] + dx];
          short8 a1 = a_s[((arow[fm + 1] + dy) * 4 + lg) * COLS + acolb[fm + 1] + dx];
          acc[fm][0]     = __builtin_amdgcn_mfma_f32_16x16x32_bf16(a0, bc[0][0], acc[fm][0], 0, 0, 0);
          acc[fm + 1][0] = __builtin_amdgcn_mfma_f32_16x16x32_bf16(a1, bc[0][0], acc[fm + 1][0], 0, 0, 0);
          acc[fm][1]     = __builtin_amdgcn_mfma_f32_16x16x32_bf16(a0, bc[0][1], acc[fm][1], 0, 0, 0);
          acc[fm + 1][1] = __builtin_amdgcn_mfma_f32_16x16x32_bf16(a1, bc[0][1], acc[fm + 1][1], 0, 0, 0);
          acc[fm][0]     = __builtin_amdgcn_mfma_f32_16x16x32_bf16(a0, bc[1][0], acc[fm][0], 0, 0, 0);
          acc[fm + 1][0] = __builtin_amdgcn_mfma_f32_16x16x32_bf16(a1, bc[1][0], acc[fm + 1][0], 0, 0, 0);
          acc[fm][1]     = __builtin_amdgcn_mfma_f32_16x16x32_bf16(a0, bc[1][1], acc[fm][1], 0, 0, 0);
          acc[fm + 1][1] = __builtin_amdgcn_mfma_f32_16x16x32_bf16(a1, bc[1][1], acc[fm + 1][1], 0, 0, 0);
        }
      } else {
#pragma unroll
        for (int fm = 0; fm < FM; ++fm) {
          short8 a = a_s[((arow[fm] + dy) * 4 + lg) * COLS + acolb[fm] + dx];
          acc[fm][0] = __builtin_amdgcn_mfma_f32_16x16x32_bf16(a, bc[0][0], acc[fm][0], 0, 0, 0);
          acc[fm][1] = __builtin_amdgcn_mfma_f32_16x16x32_bf16(a, bc[0][1], acc[fm][1], 0, 0, 0);
        }
      }
      bc[0][0] = bn_[0][0]; bc[0][1] = bn_[0][1];
      if (LO) { bc[1][0] = bn_[1][0]; bc[1][1] = bn_[1][1]; }
    }
  }

#pragma unroll
  for (int fn = 0; fn < 2; ++fn) {
    int co = cog * 64 + wn * 32 + fn * 16 + l15;
    float bs = bias[co];
#pragma unroll
    for (int fm = 0; fm < FM; ++fm) {
#pragma unroll
      for (int j = 0; j < 4; ++j) {
        int p = wm * (R * CX / 2) + fm * 16 + lg * 4 + j;
        int r = p / CX, x = p % CX;
        size_t oi = ((size_t)(b * Hout + y0 + r) * Wout + x0 + x) * Cout + co;
        if (pout) {
          pout[(size_t)ks * ((size_t)4 * Hout * Wout * Cout) + oi] = acc[fm][fn][j];
        } else {
          dst[oi] = f2b(fmaxf(acc[fm][fn][j] + bs, 0.f));
        }
      }
    }
  }
}

// combine 2 split-K partials: dst = bf16(relu(p0 + p1 + bias)), NHWC.
__global__ __launch_bounds__(256) void combine2_k(
    const float* __restrict__ p, const float* __restrict__ bias,
    bf16* __restrict__ dst, int n4, int Cout)
{
  int i = blockIdx.x * 256 + threadIdx.x;
  if (i >= n4) return;
  float4 a = reinterpret_cast<const float4*>(p)[i];
  float4 c = reinterpret_cast<const float4*>(p + (size_t)n4 * 4)[i];
  int co = (i * 4) & (Cout - 1);
  float4 bs = *reinterpret_cast<const float4*>(bias + co);
  short v0 = fbits(fmaxf(a.x + c.x + bs.x, 0.f));
  short v1 = fbits(fmaxf(a.y + c.y + bs.y, 0.f));
  short v2 = fbits(fmaxf(a.z + c.z + bs.z, 0.f));
  short v3 = fbits(fmaxf(a.w + c.w + bs.w, 0.f));
  short4 pk = make_short4(v0, v1, v2, v3);
  *reinterpret_cast<short4*>(reinterpret_cast<short*>(dst) + (size_t)i * 4) = pk;
}

// ---------------------------------------------------------------------------
// conv1a: Cin=2 VALU direct conv.
// ---------------------------------------------------------------------------
__global__ __launch_bounds__(256) void conv1a_k(
    const float* __restrict__ src, bf16* __restrict__ dst,
    const float* __restrict__ w, const float* __restrict__ bias)
{
  const int b = blockIdx.z, cog = blockIdx.y;
  const int ty0 = (blockIdx.x / 16) * 16, tx0 = (blockIdx.x % 16) * 16;
  const int tid = threadIdx.x, tx = tid & 15, ty = tid >> 4;

  __shared__ float in_s[2][18][18];
  __shared__ __align__(16) float w_s[2][3][3][16];

  for (int idx = tid; idx < 2 * 324; idx += 256) {
    int ci = idx / 324, r = idx - ci * 324;
    int iy = r / 18, ix = r - iy * 18;
    int gy = ty0 + iy - 1, gx = tx0 + ix - 1;
    float v = 0.f;
    if (gy >= 0 && gy < 256 && gx >= 0 && gx < 256)
      v = src[((size_t)(b * 2 + ci) * 512 + 2 * gy) * 512 + 2 * gx];
    in_s[ci][iy][ix] = v;
  }
  for (int idx = tid; idx < 2 * 144; idx += 256) {
    int co = idx & 15, r = idx >> 4;
    int ci = r / 9, k = r - ci * 9;
    w_s[ci][k / 3][k % 3][co] = w[(size_t)((cog * 16 + co) * 2 + ci) * 9 + k];
  }
  __syncthreads();

  float acc[16];
#pragma unroll
  for (int i = 0; i < 16; ++i) acc[i] = 0.f;
  for (int ci = 0; ci < 2; ++ci)
#pragma unroll
    for (int dy = 0; dy < 3; ++dy)
#pragma unroll
      for (int dx = 0; dx < 3; ++dx) {
        float v = in_s[ci][ty + dy][tx + dx];
        const float4* wv = (const float4*)(&w_s[ci][dy][dx][0]);
        float4 w0 = wv[0], w1 = wv[1], w2 = wv[2], w3 = wv[3];
        acc[0] = fmaf(v, w0.x, acc[0]);   acc[1] = fmaf(v, w0.y, acc[1]);
        acc[2] = fmaf(v, w0.z, acc[2]);   acc[3] = fmaf(v, w0.w, acc[3]);
        acc[4] = fmaf(v, w1.x, acc[4]);   acc[5] = fmaf(v, w1.y, acc[5]);
        acc[6] = fmaf(v, w1.z, acc[6]);   acc[7] = fmaf(v, w1.w, acc[7]);
        acc[8] = fmaf(v, w2.x, acc[8]);   acc[9] = fmaf(v, w2.y, acc[9]);
        acc[10] = fmaf(v, w2.z, acc[10]); acc[11] = fmaf(v, w2.w, acc[11]);
        acc[12] = fmaf(v, w3.x, acc[12]); acc[13] = fmaf(v, w3.y, acc[13]);
        acc[14] = fmaf(v, w3.z, acc[14]); acc[15] = fmaf(v, w3.w, acc[15]);
      }

  const int gy = ty0 + ty, gx = tx0 + tx;
  short8 s0, s1;
#pragma unroll
  for (int j = 0; j < 8; ++j) {
    s0[j] = fbits(fmaxf(acc[j] + bias[cog * 16 + j], 0.f));
    s1[j] = fbits(fmaxf(acc[8 + j] + bias[cog * 16 + 8 + j], 0.f));
  }
  short8* dp = reinterpret_cast<short8*>(
      reinterpret_cast<short*>(dst) + (((size_t)(b * 256 + gy) * 256 + gx) * 64 + cog * 16));
  dp[0] = s0; dp[1] = s1;
}

// ---------------------------------------------------------------------------
// InstanceNorm stats, 2-level (r17 vectorized stats1).
// ---------------------------------------------------------------------------
__global__ __launch_bounds__(256) void inorm_stats1_k(
    const bf16* __restrict__ x, float2* __restrict__ part,
    int HW, int C, int nb, int PC)
{
  const int b = blockIdx.y, pc = blockIdx.x;
  const int NC8 = C >> 3;
  const int pgc = 256 / NC8;
  const int c8 = (threadIdx.x % NC8) * 8;
  const int pg = threadIdx.x / NC8;
  const int chunk = HW / PC;
  const int p0 = pc * chunk;

  float s[8] = {}, ss[8] = {};
  for (int p = p0 + pg; p < p0 + chunk; p += pgc) {
    short8 v = *reinterpret_cast<const short8*>(
        reinterpret_cast<const short*>(x) + ((size_t)b * HW + p) * C + c8);
#pragma unroll
    for (int j = 0; j < 8; ++j) {
      float f = sb2f(v[j]);
      s[j] += f; ss[j] += f * f;
    }
  }
  __shared__ float sh[2][2048];
#pragma unroll
  for (int j = 0; j < 8; ++j) {
    sh[0][pg * C + c8 + j] = s[j];
    sh[1][pg * C + c8 + j] = ss[j];
  }
  __syncthreads();
  for (int c = threadIdx.x; c < C; c += 256) {
    float as = 0.f, aq = 0.f;
    for (int g = 0; g < pgc; ++g) { as += sh[0][g * C + c]; aq += sh[1][g * C + c]; }
    part[((size_t)pc * nb + b) * C + c] = make_float2(as, aq);
  }
}

__global__ __launch_bounds__(256) void inorm_stats2_k(
    const float2* __restrict__ part, float2* __restrict__ stats,
    int HW, int C, int PC, int nb)
{
  const int b = blockIdx.y, cg = blockIdx.x;
  const int c = threadIdx.x & 63, i = threadIdx.x >> 6;
  float s = 0.f, ss = 0.f;
  for (int pc = i; pc < PC; pc += 4) {
    float2 v = part[((size_t)pc * nb + b) * C + cg * 64 + c];
    s += v.x; ss += v.y;
  }
  __shared__ float sh[2][4][64];
  sh[0][i][c] = s; sh[1][i][c] = ss;
  __syncthreads();
  if (threadIdx.x < 64) {
    int cc = threadIdx.x;
    float s4 = sh[0][0][cc] + sh[0][1][cc] + sh[0][2][cc] + sh[0][3][cc];
    float q4 = sh[1][0][cc] + sh[1][1][cc] + sh[1][2][cc] + sh[1][3][cc];
    float m = s4 / (float)HW;
    float var = q4 / (float)HW - m * m;
    stats[(size_t)b * C + cg * 64 + cc] = make_float2(m, rsqrtf(var + 1e-5f));
  }
}

// generic apply: NHWC bf16 -> {NHWC bf16, NCHW f32} dests
__global__ __launch_bounds__(256) void inorm_apply_k(
    const bf16* __restrict__ x, const float2* __restrict__ stats, int HW, int C,
    bf16* __restrict__ dnhwc, float* __restrict__ fnchw)
{
  const int b = blockIdx.z, cg = blockIdx.y;
  const int c = cg * 64 + (threadIdx.x & 63);
  const int p = blockIdx.x * 4 + (threadIdx.x >> 6);
  const float2 st = stats[(size_t)b * C + c];
  const size_t ia = ((size_t)b * HW + p) * C + c;
  const float v = (b2f(x[ia]) - st.x) * st.y;
  if (dnhwc) dnhwc[ia] = f2b(v);
  if (fnchw) fnchw[((size_t)(b * C + c)) * HW + p] = v;
}

// ---------------------------------------------------------------------------
// Stage-2 apply: NHWC bf16 -> x-padded NCHW bf16 [b][c][128][144]
// ---------------------------------------------------------------------------
__global__ __launch_bounds__(256) void inorm_apply_pad_k(
    const bf16* __restrict__ x, const float2* __restrict__ stats,
    bf16* __restrict__ pad)
{
  const int b = blockIdx.z, cg = blockIdx.y, yy = blockIdx.x;
  const int tid = threadIdx.x;
  __shared__ bf16 t_s[64][130];
  __shared__ float2 st_s[64];
  if (tid < 64) st_s[tid] = stats[(size_t)b * 128 + cg * 64 + tid];
  __syncthreads();

  const int c8 = (tid & 7) * 8, px0 = tid >> 3;
#pragma unroll
  for (int pass = 0; pass < 4; ++pass) {
    int px = pass * 32 + px0;
    short8 v = *reinterpret_cast<const short8*>(
        reinterpret_cast<const short*>(x) +
        ((size_t)(b * 16384 + yy * 128 + px) * 128 + cg * 64 + c8));
#pragma unroll
    for (int j = 0; j < 8; ++j) {
      float2 st = st_s[c8 + j];
      t_s[c8 + j][px] = f2b((sb2f(v[j]) - st.x) * st.y);
    }
  }
  __syncthreads();

  for (int idx = tid; idx < 64 * 18; idx += 256) {
    int c = idx / 18, g = idx - (idx / 18) * 18;
    short8 v;
#pragma unroll
    for (int j = 0; j < 8; ++j) {
      int xx = g * 8 + j - 6;
      xx = xx < 0 ? 0 : (xx > 127 ? 127 : xx);
      v[j] = *reinterpret_cast<short*>(&t_s[c][xx]);
    }
    *reinterpret_cast<short8*>(
        reinterpret_cast<short*>(pad) +
        ((size_t)(b * 128 + cg * 64 + c) * 128 + yy) * 144 + g * 8) = v;
  }
}

// ---------------------------------------------------------------------------
// Correlation via MFMA banded GEMM. NEW: hi/lo accumulators split into
// independent chains (4 x 13-deep instead of 2 x 26-deep), merged at end.
// ---------------------------------------------------------------------------
__global__ __launch_bounds__(256) void corr_mfma_k(
    const float* __restrict__ corr, const bf16* __restrict__ pad,
    float* __restrict__ outc, bf16* __restrict__ outn, int b0)
{
  __shared__ __align__(16) char smem[26 * 64 * 16];
  short8* a_lds = reinterpret_cast<short8*>(smem);
  float* out_s = reinterpret_cast<float*>(smem);

  const int b = b0 + blockIdx.z;
  const int wg = xcd_swz(blockIdx.x, gridDim.x);
  const int y = wg >> 3, xt = wg & 7;
  const int x0 = xt * 16;
  const int tid = threadIdx.x, lane = tid & 63, wid = tid >> 6;
  const int l15 = lane & 15, lg = lane >> 4;

  for (int idx = tid; idx < 26 * 64; idx += 256) {
    short8 z = {};
    a_lds[idx] = z;
  }
  __syncthreads();

  unsigned short* ah = reinterpret_cast<unsigned short*>(a_lds);
  for (int idx = tid; idx < 169 * 16; idx += 256) {
    int t = idx >> 4, m = idx & 15;
    int dy = t / 13, dx = t - dy * 13;
    float f = corr[((size_t)b * 169 + t) * 16384 + y * 128 + x0 + m];
    bf16 hi = f2b(f);
    unsigned short hb = *reinterpret_cast<unsigned short*>(&hi);
    unsigned short lb = (unsigned short)fbits(f - b2f(hi));
    int k = m + dx;
    int ent = dy * 64 + (k >> 3) * 16 + m;
    ah[ent * 8 + (k & 7)] = hb;
    ah[(13 * 64 + ent) * 8 + (k & 7)] = lb;
  }
  __syncthreads();

  const int cg0 = wid * 2;
  f32x4 a0h = {}, a0l = {}, a1h = {}, a1l = {};
  const short* pb = reinterpret_cast<const short*>(pad);

  for (int dy = 0; dy < 13; ++dy) {
    int rowc = y + dy - 6; rowc = rowc < 0 ? 0 : (rowc > 127 ? 127 : rowc);
    short8 bhi = a_lds[dy * 64 + lane];
    short8 blo = a_lds[(13 + dy) * 64 + lane];
    size_t base0 = ((size_t)(b * 128 + cg0 * 16 + l15) * 128 + rowc) * 144
                   + x0 + lg * 8;
    short8 a0 = *reinterpret_cast<const short8*>(pb + base0);
    short8 a1 = *reinterpret_cast<const short8*>(pb + base0 + (size_t)16 * 128 * 144);
    a0h = __builtin_amdgcn_mfma_f32_16x16x32_bf16(a0, bhi, a0h, 0, 0, 0);
    a1h = __builtin_amdgcn_mfma_f32_16x16x32_bf16(a1, bhi, a1h, 0, 0, 0);
    a0l = __builtin_amdgcn_mfma_f32_16x16x32_bf16(a0, blo, a0l, 0, 0, 0);
    a1l = __builtin_amdgcn_mfma_f32_16x16x32_bf16(a1, blo, a1l, 0, 0, 0);
  }
  f32x4 acc0 = a0h + a0l, acc1 = a1h + a1l;
  __syncthreads();

#pragma unroll
  for (int cgi = 0; cgi < 2; ++cgi) {
    f32x4 a = cgi ? acc1 : acc0;
    float* dst4 = out_s + l15 * 132 + (cg0 + cgi) * 16 + lg * 4;
    *reinterpret_cast<f32x4*>(dst4) = a;
  }
  __syncthreads();

  {
    int px_ = tid >> 4, c8 = (tid & 15) * 8;
    const float* row = out_s + px_ * 132 + c8;
    short8 v;
#pragma unroll
    for (int j = 0; j < 8; ++j) v[j] = fbits(row[j]);
    *reinterpret_cast<short8*>(
        reinterpret_cast<short*>(outn) +
        ((size_t)(b * 16384 + y * 128 + x0 + px_)) * 128 + c8) = v;
  }
  {
    int ch = tid >> 1, pg = tid & 1;
    float v0[4], v1[4];
#pragma unroll
    for (int i = 0; i < 4; ++i) v0[i] = out_s[(pg * 8 + i) * 132 + ch];
#pragma unroll
    for (int i = 0; i < 4; ++i) v1[i] = out_s[(pg * 8 + 4 + i) * 132 + ch];
    float* dst = outc + ((size_t)(b * 128 + ch)) * 16384 + y * 128 + x0 + pg * 8;
    *reinterpret_cast<float4*>(dst) = make_float4(v0[0], v0[1], v0[2], v0[3]);
    *reinterpret_cast<float4*>(dst + 4) = make_float4(v1[0], v1[1], v1[2], v1[3]);
  }
}

// ---------------------------------------------------------------------------
// Workspace plan — BYTES, liveness-proven. Peak ~63.1 MB (< 67.17 proven).
// ---------------------------------------------------------------------------
extern "C" void kernel_launch(void* const* d_in, const int* in_sizes, int n_in,
                              void* d_out, int out_size, void* d_ws, size_t ws_size,
                              hipStream_t stream) {
  const float* color = (const float*)d_in[0];
  const float* corr  = (const float*)d_in[1];
  const float* w1a = (const float*)d_in[2];  const float* b1a = (const float*)d_in[3];
  const float* w1b = (const float*)d_in[4];  const float* b1b = (const float*)d_in[5];
  const float* w2a = (const float*)d_in[6];  const float* b2a = (const float*)d_in[7];
  const float* w2b = (const float*)d_in[8];  const float* b2b = (const float*)d_in[9];
  const float* w3a = (const float*)d_in[10]; const float* b3a = (const float*)d_in[11];
  const float* w3b = (const float*)d_in[12]; const float* b3b = (const float*)d_in[13];
  const float* w4a = (const float*)d_in[14]; const float* b4a = (const float*)d_in[15];
  const float* w4b = (const float*)d_in[16]; const float* b4b = (const float*)d_in[17];

  float* out = (float*)d_out;
  char* ws = (char*)d_ws;
  const size_t MB = 1048576;
  float2* stats = (float2*)ws;
  short*  WrS   = (short*)(ws + (64 << 10));
  float2* part  = (float2*)(ws + 63 * MB);
  bf16* P0 = (bf16*)(ws + 10 * MB);
  bf16* P1 = (bf16*)(ws + 27 * MB);
  bf16* P2 = (bf16*)(ws + 44 * MB);
  float* PK = (float*)(ws + 10 * MB);
  bf16* X1 = P0;
  bf16* X2 = (bf16*)d_out;
  const float2* nost = (const float2*)nullptr;
  float* nop = (float*)nullptr;

  RDesc rd;
  rd.w[0] = w1b; rd.w[1] = w2a; rd.w[2] = w2b; rd.w[3] = w3a;
  rd.w[4] = w3b; rd.w[5] = w4a; rd.w[6] = w4b;
  const int off8[7]  = {0, 9216, 27648, 64512, 101376, 175104, 322560};
  const int cin_[7]  = {64, 64, 128, 128, 256, 256, 512};
  const int cout_[7] = {64, 128, 128, 256, 256, 512, 512};
  int bases[8]; bases[0] = 0;
  const int nblk[7] = {36, 72, 144, 144, 288, 576, 1152};
  for (int i = 0; i < 7; ++i) { rd.off8[i] = off8[i]; rd.cin[i] = cin_[i];
    rd.cout[i] = cout_[i]; bases[i + 1] = bases[i] + nblk[i]; }
  for (int i = 0; i < 8; ++i) rd.base[i] = bases[i];
  const short8* WrV = (const short8*)WrS;

  // ---- ALL weight repacks in one dispatch ----
  repack_all_k<<<bases[7], 256, 0, stream>>>(rd, WrS);

  // ---- stage 1 ----
  conv1a_k<<<dim3(256, 4, 4), 256, 0, stream>>>(color, X1, w1a, b1a);
  conv_mfma_k<16, 16, 0, 1><<<1024, 256, 0, stream>>>(
      X1, X2, WrV + off8[0], b1b, nost, nop, 256, 256, 256, 64, 64, 16, 1);
  inorm_stats1_k<<<dim3(64, 4), 256, 0, stream>>>(X2, part, 65536, 64, 4, 64);
  inorm_stats2_k<<<dim3(1, 4), 256, 0, stream>>>(part, stats, 65536, 64, 64, 4);

  // ---- stage 2 ----
  conv_mfma_k<16, 16, 1, 1><<<512, 256, 0, stream>>>(
      X2, P0, WrV + off8[1], b2a, stats, nop, 256, 128, 128, 64, 128, 8, 1);
  conv_mfma_k<16, 16, 0, 1><<<512, 256, 0, stream>>>(
      P0, P1, WrV + off8[2], b2b, nost, nop, 128, 128, 128, 128, 128, 8, 1);
  inorm_stats1_k<<<dim3(64, 4), 256, 0, stream>>>(P1, part, 16384, 128, 4, 64);
  inorm_stats2_k<<<dim3(2, 4), 256, 0, stream>>>(part, stats, 16384, 128, 64, 4);
  inorm_apply_pad_k<<<dim3(128, 2, 4), 256, 0, stream>>>(P1, stats, P2);

  // ---- correlation ----
  corr_mfma_k<<<dim3(128 * 8, 1, 4), 256, 0, stream>>>(corr, P2, out, P0, 0);

  // ---- stage 3 ----
  conv_mfma_k<8, 16, 1, 0><<<512, 256, 0, stream>>>(
      P0, P1, WrV + off8[3], b3a, nost, nop, 128, 64, 64, 128, 256, 4, 1);
  conv_mfma_k<8, 16, 0, 0><<<512, 256, 0, stream>>>(
      P1, P2, WrV + off8[4], b3b, nost, nop, 64, 64, 64, 256, 256, 4, 1);
  inorm_stats1_k<<<dim3(32, 4), 256, 0, stream>>>(P2, part, 4096, 256, 4, 32);
  inorm_stats2_k<<<dim3(4, 4), 256, 0, stream>>>(part, stats, 4096, 256, 32, 4);
  inorm_apply_k<<<dim3(1024, 4, 4), 256, 0, stream>>>(
      P2, stats, 4096, 256, (bf16*)nullptr, out + 8388608);

  // ---- stage 4 ----
  conv_mfma_k<4, 16, 1, 0><<<1024, 256, 0, stream>>>(
      P2, (bf16*)nullptr, WrV + off8[5], b4a, stats, PK, 64, 32, 32, 256, 512, 2, 2);
  combine2_k<<<2048, 256, 0, stream>>>(PK, b4a, P1, 524288, 512);
  conv_mfma_k<4, 16, 0, 0><<<1024, 256, 0, stream>>>(
      P1, (bf16*)nullptr, WrV + off8[6], b4b, nost, PK, 32, 32, 32, 512, 512, 2, 2);
  combine2_k<<<2048, 256, 0, stream>>>(PK, b4b, P2, 524288, 512);
  inorm_stats1_k<<<dim3(32, 4), 256, 0, stream>>>(P2, part, 1024, 512, 4, 32);
  inorm_stats2_k<<<dim3(8, 4), 256, 0, stream>>>(part, stats, 1024, 512, 32, 4);
  inorm_apply_k<<<dim3(256, 8, 4), 256, 0, stream>>>(
      P2, stats, 1024, 512, (bf16*)nullptr, out + 12582912);
}

// Round 24
// 416.468 us; speedup vs baseline: 1.1756x; 1.0102x over previous
//
#include <hip/hip_runtime.h>
#include <hip/hip_bf16.h>

typedef __hip_bfloat16 bf16;
typedef __attribute__((ext_vector_type(8))) short short8;
typedef __attribute__((ext_vector_type(4))) float f32x4;
typedef __attribute__((address_space(1))) const void gas_void;
typedef __attribute__((address_space(3))) void las_void;

__device__ __forceinline__ float b2f(bf16 v) { return __bfloat162float(v); }
__device__ __forceinline__ bf16 f2b(float v) { return __float2bfloat16(v); }
__device__ __forceinline__ short fbits(float v) {
  bf16 h = f2b(v); return *reinterpret_cast<short*>(&h);
}
__device__ __forceinline__ float sb2f(short s) {
  return b2f(*reinterpret_cast<bf16*>(&s));
}
// bijective XCD swizzle (m204): contiguous grid chunk per XCD
__device__ __forceinline__ int xcd_swz(int bid, int nwg) {
  int q = nwg >> 3, r = nwg & 7;
  int xcd = bid & 7, idx = bid >> 3;
  return (xcd < r ? xcd * (q + 1) : r * (q + 1) + (xcd - r) * q) + idx;
}

// ---------------------------------------------------------------------------
// Mega weight repack: all 7 conv layers in ONE dispatch. Block 0 also zeros
// the 64B OOB-redirect arena slot used by the global_load_lds staging path.
// ---------------------------------------------------------------------------
struct RDesc {
  const float* w[7];
  int off8[7];
  int cin[7], cout[7];
  int base[8];
};

__global__ __launch_bounds__(256) void repack_all_k(RDesc d, short* __restrict__ Wr,
                                                    float* __restrict__ zerop)
{
  if (blockIdx.x == 0 && threadIdx.x < 16) zerop[threadIdx.x] = 0.f;
  int blk = blockIdx.x;
  int l = 0;
  while (l < 6 && blk >= d.base[l + 1]) ++l;
  const int Cin = d.cin[l], Cout = d.cout[l];
  const int nkc = Cin >> 5, ncof = Cout >> 4;
  const size_t gid = (size_t)(blk - d.base[l]) * 256 + threadIdx.x;
  const int lane = gid & 63;
  size_t r = gid >> 6;
  const int tap = r % 9; r /= 9;
  const int kcc = r % nkc; r /= nkc;
  const int cof = r % ncof;
  const int hl = r / ncof;
  const float* w = d.w[l];
  const int co = cof * 16 + (lane & 15);
  short8 v;
#pragma unroll
  for (int j = 0; j < 8; ++j) {
    int ci = kcc * 32 + ((lane >> 4) * 8 + j);
    float wv = w[((size_t)co * Cin + ci) * 9 + tap];
    bf16 hi = f2b(wv);
    v[j] = hl ? fbits(wv - b2f(hi)) : *reinterpret_cast<short*>(&hi);
  }
  *reinterpret_cast<short8*>(Wr + ((size_t)d.off8[l] + gid) * 8) = v;
}

// ---------------------------------------------------------------------------
// MFMA implicit-GEMM 3x3 conv.
// GL=1 (requires stats==null): stage A-tile via __builtin_amdgcn_global_load_lds
// 16B — LDS dest linear in slot index (wave-uniform base + lane*16, m104);
// OOB lanes redirect to a zeroed arena slot (broadcast read). Slot->granule
// map inverts slot_of, so LDS bytes are bit-identical to the reg path.
// GL=0: reg staging (used when inorm apply is fused via `stats`).
// LO=1: hi+lo weight pair, fm-pair issue order. Split-K via KS.
// ---------------------------------------------------------------------------
template<int R, int CX, int S, int LO, int GL>
__global__ __launch_bounds__(256) void conv_mfma_k(
    const bf16* __restrict__ src, bf16* __restrict__ dst,
    const short8* __restrict__ Wr, const float* __restrict__ bias,
    const float2* __restrict__ stats, float* __restrict__ pout,
    const float* __restrict__ zerop,
    int Win, int Hout, int Wout, int Cin, int Cout, int XT, int KS)
{
  constexpr int ROWS = R + 2;
  constexpr int COLS = CX + 2;
  constexpr int NGR = ROWS * 4 * COLS;
  constexpr int FM = (R * CX) / 32;
  __shared__ short8 a_s[NGR];

  const int ytn = Hout / R;
  const int nxy = XT * ytn;
  const int ncog = Cout >> 6;
  const int wg = xcd_swz(blockIdx.x, gridDim.x);
  const int ks = wg / (ncog * 4 * nxy);
  const int rem2 = wg - ks * (ncog * 4 * nxy);
  const int cog = rem2 / (4 * nxy);
  const int rem = rem2 - cog * (4 * nxy);
  const int b = rem / nxy;
  const int pxb = rem - b * nxy;
  const int xt = pxb % XT, yt = pxb / XT;
  const int x0 = xt * CX, y0 = yt * R;

  const int tid = threadIdx.x, lane = tid & 63, wid = tid >> 6;
  const int wm = wid & 1, wn = wid >> 1;
  const int nkc = Cin >> 5;
  const int nkcs = nkc / KS;
  const int kc0 = ks * nkcs;
  const int ncof = Cout >> 4;
  const int l15 = lane & 15, lg = lane >> 4;

  f32x4 acc[FM][2] = {};

  int arow[FM], acolb[FM];
#pragma unroll
  for (int fm = 0; fm < FM; ++fm) {
    int p = wm * (R * CX / 2) + fm * 16 + l15;
    arow[fm] = p / CX;
    acolb[fm] = p % CX;
  }

  auto bload = [&](int hl, int fn, int kcc, int tap) -> short8 {
    int cof = cog * 4 + wn * 2 + fn;
    return Wr[((((size_t)hl * ncof + cof) * nkc + kcc) * 9 + tap) * 64 + lane];
  };

  short8 bc[2][2], bn_[2][2];
  bc[0][0] = bload(0, 0, kc0, 0); bc[0][1] = bload(0, 1, kc0, 0);
  if (LO) { bc[1][0] = bload(1, 0, kc0, 0); bc[1][1] = bload(1, 1, kc0, 0); }

  for (int kc = kc0; kc < kc0 + nkcs; ++kc) {
    __syncthreads();
    if (GL) {
      // direct global->LDS, slot-linear issue order
      for (int s = tid; s < NGR; s += 256) {
        int col = s % COLS, rg = s / COLS;
        int row = rg >> 2, g = rg & 3;
        int sy = y0 + row - 1;
        int sx = x0 + col - 1;
        const short* gp;
        if (sy >= 0 && sy < Hout && sx >= 0 && sx < Wout) {
          int ry = S ? 2 * sy : sy, rx = S ? 2 * sx : sx;
          gp = reinterpret_cast<const short*>(src) +
               (((size_t)b * (S ? 2 * Hout : Hout) + ry) * Win + rx) * Cin +
               kc * 32 + g * 8;
        } else {
          gp = reinterpret_cast<const short*>(zerop);   // 16B zeros (broadcast)
        }
        __builtin_amdgcn_global_load_lds((gas_void*)gp, (las_void*)&a_s[s], 16, 0, 0);
      }
    } else {
      for (int idx = tid; idx < NGR; idx += 256) {
        int g = idx & 3, cix = idx >> 2;
        int col = cix % COLS, row = cix / COLS;
        int sy = y0 + row - 1;
        int sx = x0 + col - 1;
        short8 v = {};
        if (sy >= 0 && sy < Hout && sx >= 0 && sx < Wout) {
          int ry = S ? 2 * sy : sy, rx = S ? 2 * sx : sx;
          v = *reinterpret_cast<const short8*>(
              reinterpret_cast<const short*>(src) +
              (((size_t)b * (S ? 2 * Hout : Hout) + ry) * Win + rx) * Cin +
              kc * 32 + g * 8);
          if (stats) {                   // fused inorm apply (bit-exact)
            const float2* st = stats + (size_t)b * Cin + kc * 32 + g * 8;
#pragma unroll
            for (int j = 0; j < 8; ++j)
              v[j] = fbits((sb2f(v[j]) - st[j].x) * st[j].y);
          }
        }
        a_s[(row * 4 + g) * COLS + col] = v;
      }
    }
    __syncthreads();

#pragma unroll
    for (int tap = 0; tap < 9; ++tap) {
      const int dy = tap / 3, dx = tap % 3;
      int nt = tap + 1, nk = kc;
      if (nt == 9) { nt = 0; nk = (kc + 1 < kc0 + nkcs) ? kc + 1 : kc0; }
      bn_[0][0] = bload(0, 0, nk, nt); bn_[0][1] = bload(0, 1, nk, nt);
      if (LO) { bn_[1][0] = bload(1, 0, nk, nt); bn_[1][1] = bload(1, 1, nk, nt); }
      if (LO) {
#pragma unroll
        for (int fm = 0; fm < FM; fm += 2) {
          short8 a0 = a_s[((arow[fm] + dy) * 4 + lg) * COLS + acolb[fm] + dx];
          short8 a1 = a_s[((arow[fm + 1] + dy) * 4 + lg) * COLS + acolb[fm + 1] + dx];
          acc[fm][0]     = __builtin_amdgcn_mfma_f32_16x16x32_bf16(a0, bc[0][0], acc[fm][0], 0, 0, 0);
          acc[fm + 1][0] = __builtin_amdgcn_mfma_f32_16x16x32_bf16(a1, bc[0][0], acc[fm + 1][0], 0, 0, 0);
          acc[fm][1]     = __builtin_amdgcn_mfma_f32_16x16x32_bf16(a0, bc[0][1], acc[fm][1], 0, 0, 0);
          acc[fm + 1][1] = __builtin_amdgcn_mfma_f32_16x16x32_bf16(a1, bc[0][1], acc[fm + 1][1], 0, 0, 0);
          acc[fm][0]     = __builtin_amdgcn_mfma_f32_16x16x32_bf16(a0, bc[1][0], acc[fm][0], 0, 0, 0);
          acc[fm + 1][0] = __builtin_amdgcn_mfma_f32_16x16x32_bf16(a1, bc[1][0], acc[fm + 1][0], 0, 0, 0);
          acc[fm][1]     = __builtin_amdgcn_mfma_f32_16x16x32_bf16(a0, bc[1][1], acc[fm][1], 0, 0, 0);
          acc[fm + 1][1] = __builtin_amdgcn_mfma_f32_16x16x32_bf16(a1, bc[1][1], acc[fm + 1][1], 0, 0, 0);
        }
      } else {
#pragma unroll
        for (int fm = 0; fm < FM; ++fm) {
          short8 a = a_s[((arow[fm] + dy) * 4 + lg) * COLS + acolb[fm] + dx];
          acc[fm][0] = __builtin_amdgcn_mfma_f32_16x16x32_bf16(a, bc[0][0], acc[fm][0], 0, 0, 0);
          acc[fm][1] = __builtin_amdgcn_mfma_f32_16x16x32_bf16(a, bc[0][1], acc[fm][1], 0, 0, 0);
        }
      }
      bc[0][0] = bn_[0][0]; bc[0][1] = bn_[0][1];
      if (LO) { bc[1][0] = bn_[1][0]; bc[1][1] = bn_[1][1]; }
    }
  }

#pragma unroll
  for (int fn = 0; fn < 2; ++fn) {
    int co = cog * 64 + wn * 32 + fn * 16 + l15;
    float bs = bias[co];
#pragma unroll
    for (int fm = 0; fm < FM; ++fm) {
#pragma unroll
      for (int j = 0; j < 4; ++j) {
        int p = wm * (R * CX / 2) + fm * 16 + lg * 4 + j;
        int r = p / CX, x = p % CX;
        size_t oi = ((size_t)(b * Hout + y0 + r) * Wout + x0 + x) * Cout + co;
        if (pout) {
          pout[(size_t)ks * ((size_t)4 * Hout * Wout * Cout) + oi] = acc[fm][fn][j];
        } else {
          dst[oi] = f2b(fmaxf(acc[fm][fn][j] + bs, 0.f));
        }
      }
    }
  }
}

// combine 2 split-K partials: dst = bf16(relu(p0 + p1 + bias)), NHWC.
__global__ __launch_bounds__(256) void combine2_k(
    const float* __restrict__ p, const float* __restrict__ bias,
    bf16* __restrict__ dst, int n4, int Cout)
{
  int i = blockIdx.x * 256 + threadIdx.x;
  if (i >= n4) return;
  float4 a = reinterpret_cast<const float4*>(p)[i];
  float4 c = reinterpret_cast<const float4*>(p + (size_t)n4 * 4)[i];
  int co = (i * 4) & (Cout - 1);
  float4 bs = *reinterpret_cast<const float4*>(bias + co);
  short v0 = fbits(fmaxf(a.x + c.x + bs.x, 0.f));
  short v1 = fbits(fmaxf(a.y + c.y + bs.y, 0.f));
  short v2 = fbits(fmaxf(a.z + c.z + bs.z, 0.f));
  short v3 = fbits(fmaxf(a.w + c.w + bs.w, 0.f));
  short4 pk = make_short4(v0, v1, v2, v3);
  *reinterpret_cast<short4*>(reinterpret_cast<short*>(dst) + (size_t)i * 4) = pk;
}

// ---------------------------------------------------------------------------
// conv1a: Cin=2 VALU direct conv.
// ---------------------------------------------------------------------------
__global__ __launch_bounds__(256) void conv1a_k(
    const float* __restrict__ src, bf16* __restrict__ dst,
    const float* __restrict__ w, const float* __restrict__ bias)
{
  const int b = blockIdx.z, cog = blockIdx.y;
  const int ty0 = (blockIdx.x / 16) * 16, tx0 = (blockIdx.x % 16) * 16;
  const int tid = threadIdx.x, tx = tid & 15, ty = tid >> 4;

  __shared__ float in_s[2][18][18];
  __shared__ __align__(16) float w_s[2][3][3][16];

  for (int idx = tid; idx < 2 * 324; idx += 256) {
    int ci = idx / 324, r = idx - ci * 324;
    int iy = r / 18, ix = r - iy * 18;
    int gy = ty0 + iy - 1, gx = tx0 + ix - 1;
    float v = 0.f;
    if (gy >= 0 && gy < 256 && gx >= 0 && gx < 256)
      v = src[((size_t)(b * 2 + ci) * 512 + 2 * gy) * 512 + 2 * gx];
    in_s[ci][iy][ix] = v;
  }
  for (int idx = tid; idx < 2 * 144; idx += 256) {
    int co = idx & 15, r = idx >> 4;
    int ci = r / 9, k = r - ci * 9;
    w_s[ci][k / 3][k % 3][co] = w[(size_t)((cog * 16 + co) * 2 + ci) * 9 + k];
  }
  __syncthreads();

  float acc[16];
#pragma unroll
  for (int i = 0; i < 16; ++i) acc[i] = 0.f;
  for (int ci = 0; ci < 2; ++ci)
#pragma unroll
    for (int dy = 0; dy < 3; ++dy)
#pragma unroll
      for (int dx = 0; dx < 3; ++dx) {
        float v = in_s[ci][ty + dy][tx + dx];
        const float4* wv = (const float4*)(&w_s[ci][dy][dx][0]);
        float4 w0 = wv[0], w1 = wv[1], w2 = wv[2], w3 = wv[3];
        acc[0] = fmaf(v, w0.x, acc[0]);   acc[1] = fmaf(v, w0.y, acc[1]);
        acc[2] = fmaf(v, w0.z, acc[2]);   acc[3] = fmaf(v, w0.w, acc[3]);
        acc[4] = fmaf(v, w1.x, acc[4]);   acc[5] = fmaf(v, w1.y, acc[5]);
        acc[6] = fmaf(v, w1.z, acc[6]);   acc[7] = fmaf(v, w1.w, acc[7]);
        acc[8] = fmaf(v, w2.x, acc[8]);   acc[9] = fmaf(v, w2.y, acc[9]);
        acc[10] = fmaf(v, w2.z, acc[10]); acc[11] = fmaf(v, w2.w, acc[11]);
        acc[12] = fmaf(v, w3.x, acc[12]); acc[13] = fmaf(v, w3.y, acc[13]);
        acc[14] = fmaf(v, w3.z, acc[14]); acc[15] = fmaf(v, w3.w, acc[15]);
      }

  const int gy = ty0 + ty, gx = tx0 + tx;
  short8 s0, s1;
#pragma unroll
  for (int j = 0; j < 8; ++j) {
    s0[j] = fbits(fmaxf(acc[j] + bias[cog * 16 + j], 0.f));
    s1[j] = fbits(fmaxf(acc[8 + j] + bias[cog * 16 + 8 + j], 0.f));
  }
  short8* dp = reinterpret_cast<short8*>(
      reinterpret_cast<short*>(dst) + (((size_t)(b * 256 + gy) * 256 + gx) * 64 + cog * 16));
  dp[0] = s0; dp[1] = s1;
}

// ---------------------------------------------------------------------------
// InstanceNorm stats, 2-level (r17 vectorized stats1).
// ---------------------------------------------------------------------------
__global__ __launch_bounds__(256) void inorm_stats1_k(
    const bf16* __restrict__ x, float2* __restrict__ part,
    int HW, int C, int nb, int PC)
{
  const int b = blockIdx.y, pc = blockIdx.x;
  const int NC8 = C >> 3;
  const int pgc = 256 / NC8;
  const int c8 = (threadIdx.x % NC8) * 8;
  const int pg = threadIdx.x / NC8;
  const int chunk = HW / PC;
  const int p0 = pc * chunk;

  float s[8] = {}, ss[8] = {};
  for (int p = p0 + pg; p < p0 + chunk; p += pgc) {
    short8 v = *reinterpret_cast<const short8*>(
        reinterpret_cast<const short*>(x) + ((size_t)b * HW + p) * C + c8);
#pragma unroll
    for (int j = 0; j < 8; ++j) {
      float f = sb2f(v[j]);
      s[j] += f; ss[j] += f * f;
    }
  }
  __shared__ float sh[2][2048];
#pragma unroll
  for (int j = 0; j < 8; ++j) {
    sh[0][pg * C + c8 + j] = s[j];
    sh[1][pg * C + c8 + j] = ss[j];
  }
  __syncthreads();
  for (int c = threadIdx.x; c < C; c += 256) {
    float as = 0.f, aq = 0.f;
    for (int g = 0; g < pgc; ++g) { as += sh[0][g * C + c]; aq += sh[1][g * C + c]; }
    part[((size_t)pc * nb + b) * C + c] = make_float2(as, aq);
  }
}

__global__ __launch_bounds__(256) void inorm_stats2_k(
    const float2* __restrict__ part, float2* __restrict__ stats,
    int HW, int C, int PC, int nb)
{
  const int b = blockIdx.y, cg = blockIdx.x;
  const int c = threadIdx.x & 63, i = threadIdx.x >> 6;
  float s = 0.f, ss = 0.f;
  for (int pc = i; pc < PC; pc += 4) {
    float2 v = part[((size_t)pc * nb + b) * C + cg * 64 + c];
    s += v.x; ss += v.y;
  }
  __shared__ float sh[2][4][64];
  sh[0][i][c] = s; sh[1][i][c] = ss;
  __syncthreads();
  if (threadIdx.x < 64) {
    int cc = threadIdx.x;
    float s4 = sh[0][0][cc] + sh[0][1][cc] + sh[0][2][cc] + sh[0][3][cc];
    float q4 = sh[1][0][cc] + sh[1][1][cc] + sh[1][2][cc] + sh[1][3][cc];
    float m = s4 / (float)HW;
    float var = q4 / (float)HW - m * m;
    stats[(size_t)b * C + cg * 64 + cc] = make_float2(m, rsqrtf(var + 1e-5f));
  }
}

// generic apply: NHWC bf16 -> {NHWC bf16, NCHW f32} dests
__global__ __launch_bounds__(256) void inorm_apply_k(
    const bf16* __restrict__ x, const float2* __restrict__ stats, int HW, int C,
    bf16* __restrict__ dnhwc, float* __restrict__ fnchw)
{
  const int b = blockIdx.z, cg = blockIdx.y;
  const int c = cg * 64 + (threadIdx.x & 63);
  const int p = blockIdx.x * 4 + (threadIdx.x >> 6);
  const float2 st = stats[(size_t)b * C + c];
  const size_t ia = ((size_t)b * HW + p) * C + c;
  const float v = (b2f(x[ia]) - st.x) * st.y;
  if (dnhwc) dnhwc[ia] = f2b(v);
  if (fnchw) fnchw[((size_t)(b * C + c)) * HW + p] = v;
}

// ---------------------------------------------------------------------------
// Stage-2 apply: NHWC bf16 -> x-padded NCHW bf16 [b][c][128][144]
// ---------------------------------------------------------------------------
__global__ __launch_bounds__(256) void inorm_apply_pad_k(
    const bf16* __restrict__ x, const float2* __restrict__ stats,
    bf16* __restrict__ pad)
{
  const int b = blockIdx.z, cg = blockIdx.y, yy = blockIdx.x;
  const int tid = threadIdx.x;
  __shared__ bf16 t_s[64][130];
  __shared__ float2 st_s[64];
  if (tid < 64) st_s[tid] = stats[(size_t)b * 128 + cg * 64 + tid];
  __syncthreads();

  const int c8 = (tid & 7) * 8, px0 = tid >> 3;
#pragma unroll
  for (int pass = 0; pass < 4; ++pass) {
    int px = pass * 32 + px0;
    short8 v = *reinterpret_cast<const short8*>(
        reinterpret_cast<const short*>(x) +
        ((size_t)(b * 16384 + yy * 128 + px) * 128 + cg * 64 + c8));
#pragma unroll
    for (int j = 0; j < 8; ++j) {
      float2 st = st_s[c8 + j];
      t_s[c8 + j][px] = f2b((sb2f(v[j]) - st.x) * st.y);
    }
  }
  __syncthreads();

  for (int idx = tid; idx < 64 * 18; idx += 256) {
    int c = idx / 18, g = idx - (idx / 18) * 18;
    short8 v;
#pragma unroll
    for (int j = 0; j < 8; ++j) {
      int xx = g * 8 + j - 6;
      xx = xx < 0 ? 0 : (xx > 127 ? 127 : xx);
      v[j] = *reinterpret_cast<short*>(&t_s[c][xx]);
    }
    *reinterpret_cast<short8*>(
        reinterpret_cast<short*>(pad) +
        ((size_t)(b * 128 + cg * 64 + c) * 128 + yy) * 144 + g * 8) = v;
  }
}

// ---------------------------------------------------------------------------
// Correlation via MFMA banded GEMM (r23 structure, split hi/lo chains).
// ---------------------------------------------------------------------------
__global__ __launch_bounds__(256) void corr_mfma_k(
    const float* __restrict__ corr, const bf16* __restrict__ pad,
    float* __restrict__ outc, bf16* __restrict__ outn, int b0)
{
  __shared__ __align__(16) char smem[26 * 64 * 16];
  short8* a_lds = reinterpret_cast<short8*>(smem);
  float* out_s = reinterpret_cast<float*>(smem);

  const int b = b0 + blockIdx.z;
  const int wg = xcd_swz(blockIdx.x, gridDim.x);
  const int y = wg >> 3, xt = wg & 7;
  const int x0 = xt * 16;
  const int tid = threadIdx.x, lane = tid & 63, wid = tid >> 6;
  const int l15 = lane & 15, lg = lane >> 4;

  for (int idx = tid; idx < 26 * 64; idx += 256) {
    short8 z = {};
    a_lds[idx] = z;
  }
  __syncthreads();

  unsigned short* ah = reinterpret_cast<unsigned short*>(a_lds);
  for (int idx = tid; idx < 169 * 16; idx += 256) {
    int t = idx >> 4, m = idx & 15;
    int dy = t / 13, dx = t - dy * 13;
    float f = corr[((size_t)b * 169 + t) * 16384 + y * 128 + x0 + m];
    bf16 hi = f2b(f);
    unsigned short hb = *reinterpret_cast<unsigned short*>(&hi);
    unsigned short lb = (unsigned short)fbits(f - b2f(hi));
    int k = m + dx;
    int ent = dy * 64 + (k >> 3) * 16 + m;
    ah[ent * 8 + (k & 7)] = hb;
    ah[(13 * 64 + ent) * 8 + (k & 7)] = lb;
  }
  __syncthreads();

  const int cg0 = wid * 2;
  f32x4 a0h = {}, a0l = {}, a1h = {}, a1l = {};
  const short* pb = reinterpret_cast<const short*>(pad);

  for (int dy = 0; dy < 13; ++dy) {
    int rowc = y + dy - 6; rowc = rowc < 0 ? 0 : (rowc > 127 ? 127 : rowc);
    short8 bhi = a_lds[dy * 64 + lane];
    short8 blo = a_lds[(13 + dy) * 64 + lane];
    size_t base0 = ((size_t)(b * 128 + cg0 * 16 + l15) * 128 + rowc) * 144
                   + x0 + lg * 8;
    short8 a0 = *reinterpret_cast<const short8*>(pb + base0);
    short8 a1 = *reinterpret_cast<const short8*>(pb + base0 + (size_t)16 * 128 * 144);
    a0h = __builtin_amdgcn_mfma_f32_16x16x32_bf16(a0, bhi, a0h, 0, 0, 0);
    a1h = __builtin_amdgcn_mfma_f32_16x16x32_bf16(a1, bhi, a1h, 0, 0, 0);
    a0l = __builtin_amdgcn_mfma_f32_16x16x32_bf16(a0, blo, a0l, 0, 0, 0);
    a1l = __builtin_amdgcn_mfma_f32_16x16x32_bf16(a1, blo, a1l, 0, 0, 0);
  }
  f32x4 acc0 = a0h + a0l, acc1 = a1h + a1l;
  __syncthreads();

#pragma unroll
  for (int cgi = 0; cgi < 2; ++cgi) {
    f32x4 a = cgi ? acc1 : acc0;
    float* dst4 = out_s + l15 * 132 + (cg0 + cgi) * 16 + lg * 4;
    *reinterpret_cast<f32x4*>(dst4) = a;
  }
  __syncthreads();

  {
    int px_ = tid >> 4, c8 = (tid & 15) * 8;
    const float* row = out_s + px_ * 132 + c8;
    short8 v;
#pragma unroll
    for (int j = 0; j < 8; ++j) v[j] = fbits(row[j]);
    *reinterpret_cast<short8*>(
        reinterpret_cast<short*>(outn) +
        ((size_t)(b * 16384 + y * 128 + x0 + px_)) * 128 + c8) = v;
  }
  {
    int ch = tid >> 1, pg = tid & 1;
    float v0[4], v1[4];
#pragma unroll
    for (int i = 0; i < 4; ++i) v0[i] = out_s[(pg * 8 + i) * 132 + ch];
#pragma unroll
    for (int i = 0; i < 4; ++i) v1[i] = out_s[(pg * 8 + 4 + i) * 132 + ch];
    float* dst = outc + ((size_t)(b * 128 + ch)) * 16384 + y * 128 + x0 + pg * 8;
    *reinterpret_cast<float4*>(dst) = make_float4(v0[0], v0[1], v0[2], v0[3]);
    *reinterpret_cast<float4*>(dst + 4) = make_float4(v1[0], v1[1], v1[2], v1[3]);
  }
}

// ---------------------------------------------------------------------------
// Workspace plan — BYTES, liveness-proven. Peak ~63.8 MB (< 67.17 proven).
//   stats@0 (16KB); Wr@64KB (9.42MB); P0@10MB; P1@27MB; P2@44MB (18.87MB);
//   part@63MB (512KB); zeropad@63.8MB (64B). PK=P0 in stage 4.
// ---------------------------------------------------------------------------
extern "C" void kernel_launch(void* const* d_in, const int* in_sizes, int n_in,
                              void* d_out, int out_size, void* d_ws, size_t ws_size,
                              hipStream_t stream) {
  const float* color = (const float*)d_in[0];
  const float* corr  = (const float*)d_in[1];
  const float* w1a = (const float*)d_in[2];  const float* b1a = (const float*)d_in[3];
  const float* w1b = (const float*)d_in[4];  const float* b1b = (const float*)d_in[5];
  const float* w2a = (const float*)d_in[6];  const float* b2a = (const float*)d_in[7];
  const float* w2b = (const float*)d_in[8];  const float* b2b = (const float*)d_in[9];
  const float* w3a = (const float*)d_in[10]; const float* b3a = (const float*)d_in[11];
  const float* w3b = (const float*)d_in[12]; const float* b3b = (const float*)d_in[13];
  const float* w4a = (const float*)d_in[14]; const float* b4a = (const float*)d_in[15];
  const float* w4b = (const float*)d_in[16]; const float* b4b = (const float*)d_in[17];

  float* out = (float*)d_out;
  char* ws = (char*)d_ws;
  const size_t MB = 1048576;
  float2* stats = (float2*)ws;
  short*  WrS   = (short*)(ws + (64 << 10));
  float2* part  = (float2*)(ws + 63 * MB);
  float*  zerop = (float*)(ws + 63 * MB + (800 << 10));
  bf16* P0 = (bf16*)(ws + 10 * MB);
  bf16* P1 = (bf16*)(ws + 27 * MB);
  bf16* P2 = (bf16*)(ws + 44 * MB);
  float* PK = (float*)(ws + 10 * MB);
  bf16* X1 = P0;
  bf16* X2 = (bf16*)d_out;
  const float2* nost = (const float2*)nullptr;
  float* nop = (float*)nullptr;

  RDesc rd;
  rd.w[0] = w1b; rd.w[1] = w2a; rd.w[2] = w2b; rd.w[3] = w3a;
  rd.w[4] = w3b; rd.w[5] = w4a; rd.w[6] = w4b;
  const int off8[7]  = {0, 9216, 27648, 64512, 101376, 175104, 322560};
  const int cin_[7]  = {64, 64, 128, 128, 256, 256, 512};
  const int cout_[7] = {64, 128, 128, 256, 256, 512, 512};
  int bases[8]; bases[0] = 0;
  const int nblk[7] = {36, 72, 144, 144, 288, 576, 1152};
  for (int i = 0; i < 7; ++i) { rd.off8[i] = off8[i]; rd.cin[i] = cin_[i];
    rd.cout[i] = cout_[i]; bases[i + 1] = bases[i] + nblk[i]; }
  for (int i = 0; i < 8; ++i) rd.base[i] = bases[i];
  const short8* WrV = (const short8*)WrS;

  // ---- ALL weight repacks (+ zeropad init) in one dispatch ----
  repack_all_k<<<bases[7], 256, 0, stream>>>(rd, WrS, zerop);

  // ---- stage 1 ----
  conv1a_k<<<dim3(256, 4, 4), 256, 0, stream>>>(color, X1, w1a, b1a);
  conv_mfma_k<16, 16, 0, 1, 1><<<1024, 256, 0, stream>>>(
      X1, X2, WrV + off8[0], b1b, nost, nop, zerop, 256, 256, 256, 64, 64, 16, 1);
  inorm_stats1_k<<<dim3(64, 4), 256, 0, stream>>>(X2, part, 65536, 64, 4, 64);
  inorm_stats2_k<<<dim3(1, 4), 256, 0, stream>>>(part, stats, 65536, 64, 64, 4);

  // ---- stage 2 ----
  conv_mfma_k<16, 16, 1, 1, 0><<<512, 256, 0, stream>>>(
      X2, P0, WrV + off8[1], b2a, stats, nop, zerop, 256, 128, 128, 64, 128, 8, 1);
  conv_mfma_k<16, 16, 0, 1, 1><<<512, 256, 0, stream>>>(
      P0, P1, WrV + off8[2], b2b, nost, nop, zerop, 128, 128, 128, 128, 128, 8, 1);
  inorm_stats1_k<<<dim3(64, 4), 256, 0, stream>>>(P1, part, 16384, 128, 4, 64);
  inorm_stats2_k<<<dim3(2, 4), 256, 0, stream>>>(part, stats, 16384, 128, 64, 4);
  inorm_apply_pad_k<<<dim3(128, 2, 4), 256, 0, stream>>>(P1, stats, P2);

  // ---- correlation ----
  corr_mfma_k<<<dim3(128 * 8, 1, 4), 256, 0, stream>>>(corr, P2, out, P0, 0);

  // ---- stage 3 ----
  conv_mfma_k<8, 16, 1, 0, 1><<<512, 256, 0, stream>>>(
      P0, P1, WrV + off8[3], b3a, nost, nop, zerop, 128, 64, 64, 128, 256, 4, 1);
  conv_mfma_k<8, 16, 0, 0, 1><<<512, 256, 0, stream>>>(
      P1, P2, WrV + off8[4], b3b, nost, nop, zerop, 64, 64, 64, 256, 256, 4, 1);
  inorm_stats1_k<<<dim3(32, 4), 256, 0, stream>>>(P2, part, 4096, 256, 4, 32);
  inorm_stats2_k<<<dim3(4, 4), 256, 0, stream>>>(part, stats, 4096, 256, 32, 4);
  inorm_apply_k<<<dim3(1024, 4, 4), 256, 0, stream>>>(
      P2, stats, 4096, 256, (bf16*)nullptr, out + 8388608);

  // ---- stage 4 ----
  conv_mfma_k<4, 16, 1, 0, 0><<<1024, 256, 0, stream>>>(
      P2, (bf16*)nullptr, WrV + off8[5], b4a, stats, PK, zerop, 64, 32, 32, 256, 512, 2, 2);
  combine2_k<<<2048, 256, 0, stream>>>(PK, b4a, P1, 524288, 512);
  conv_mfma_k<4, 16, 0, 0, 1><<<1024, 256, 0, stream>>>(
      P1, (bf16*)nullptr, WrV + off8[6], b4b, nost, PK, zerop, 32, 32, 32, 512, 512, 2, 2);
  combine2_k<<<2048, 256, 0, stream>>>(PK, b4b, P2, 524288, 512);
  inorm_stats1_k<<<dim3(32, 4), 256, 0, stream>>>(P2, part, 1024, 512, 4, 32);
  inorm_stats2_k<<<dim3(8, 4), 256, 0, stream>>>(part, stats, 1024, 512, 32, 4);
  inorm_apply_k<<<dim3(256, 8, 4), 256, 0, stream>>>(
      P2, stats, 1024, 512, (bf16*)nullptr, out + 12582912);
}